// Round 3
// baseline (699.086 us; speedup 1.0000x reference)
//
#include <hip/hip_runtime.h>

// ---------------------------------------------------------------------------
// Types / helpers
// ---------------------------------------------------------------------------
typedef short s16x8 __attribute__((ext_vector_type(8)));
typedef short s16x4 __attribute__((ext_vector_type(4)));
typedef float f32x4 __attribute__((ext_vector_type(4)));
typedef __bf16 bf16x8 __attribute__((ext_vector_type(8)));

__device__ __forceinline__ float bf2f(short u) {
  union { unsigned int i; float f; } c;
  c.i = ((unsigned int)(unsigned short)u) << 16;
  return c.f;
}
__device__ __forceinline__ short f2bf(float f) {
  union { float f; unsigned int i; } c; c.f = f;
  unsigned int r = c.i + 0x7FFFu + ((c.i >> 16) & 1u);  // RNE
  return (short)(r >> 16);
}
__device__ __forceinline__ float sigmoidf_(float x) { return 1.f / (1.f + __expf(-x)); }

// MFMA bf16 16x16x32 — SFINAE shim: works whether the builtin wants short8 or bf16x8.
template <typename T>
__device__ __forceinline__ auto mfma_sel(T a, T b, f32x4 c, int)
    -> decltype(__builtin_amdgcn_mfma_f32_16x16x32_bf16(a, b, c, 0, 0, 0)) {
  return __builtin_amdgcn_mfma_f32_16x16x32_bf16(a, b, c, 0, 0, 0);
}
template <typename T>
__device__ __forceinline__ f32x4 mfma_sel(T a, T b, f32x4 c, long) {
  return __builtin_amdgcn_mfma_f32_16x16x32_bf16(
      __builtin_bit_cast(bf16x8, a), __builtin_bit_cast(bf16x8, b), c, 0, 0, 0);
}
__device__ __forceinline__ f32x4 MFMA16(s16x8 a, s16x8 b, f32x4 c) {
  return mfma_sel(a, b, c, 0);
}

__device__ __forceinline__ void gl2lds16(const void* g, void* l) {
  __builtin_amdgcn_global_load_lds(
      (const __attribute__((address_space(1))) unsigned int*)g,
      (__attribute__((address_space(3))) unsigned int*)l, 16, 0, 0);
}

// ---------------------------------------------------------------------------
// Workspace layout (byte offsets)
// ---------------------------------------------------------------------------
#define OFF_WADA1    0u             // [1536][768] bf16 (scale^T | shift^T)
#define OFF_WQKVG    2359296u       // [3072][768] bf16 (q|k|v|g ^T)
#define OFF_WO       7077888u       // [768][768]
#define OFF_WGATES   8257536u       // [1536][768] (op^T | tr_out^T)
#define OFF_WTMPQKV  10616832u      // [2304][768]
#define OFF_WTMPO    14155776u      // [768][768]
#define OFF_WADA2    15335424u      // [1536][768]
#define OFF_WTRANS   17694720u      // [3072][768] (gate^T | ab^T)
#define OFF_WBA      22413312u      // [768][1536]
#define OFF_BIAS     24772608u      // 9984 floats
#define OFF_ZT       24812544u      // [2][12][256][256] bf16 (3 MB)
#define OFF_AN1      31104000u      // bf16 [8192][768]  (an1 / h)
#define OFF_SN1      43686912u      // bf16 [8192][768]  (sn1 / an2)
#define OFF_SN2      56269824u      // bf16 [8192][768]
#define OFF_SBF      68852736u      // bf16 [8192][768]  (s_bf / b_act / b2)
#define OFF_CADA     81435648u      // bf16 [8192][1536] (hid)
#define OFF_QKVG     106601472u     // bf16 [8192][3072] (qkvg / qkvt)
#define OFF_GATES    156933120u     // bf16 [8192][1536] (sigmoid gates: op | tr)
#define OFF_OGO      182098944u     // bf16 [8192][768]  (gated attn out / tattn)
#define OFF_A1       194681856u     // f32  [8192][768]  (a1, then a2 in-place)

// ---------------------------------------------------------------------------
// Weight prep: transpose fp32 [K][N] -> bf16 [N][K] into ws
// ---------------------------------------------------------------------------
__global__ __launch_bounds__(256) void prep_weights(
    const float* p0, const float* p1, const float* p2, const float* p3,
    const float* p4, const float* p5, const float* p6, const float* p7,
    const float* p8, const float* p9, const float* p10, const float* p11,
    const float* p12, const float* p13, const float* p14, const float* p15,
    const float* p16, const float* p17, short* wsb) {
  struct E { int K, N, dst; };
  const E tab[18] = {
      {768, 768, 0},        {768, 768, 589824},
      {768, 768, 1179648},  {768, 768, 1769472},
      {768, 768, 2359296},  {768, 768, 2949120},
      {768, 768, 3538944},
      {768, 768, 4128768},  {768, 768, 4718592},
      {768, 768, 7667712},  {768, 768, 8257536},
      {768, 1536, 8847360}, {768, 1536, 10027008},
      {1536, 768, 11206656},
      {768, 768, 5308416},  {768, 768, 5898240}, {768, 768, 6488064},
      {768, 768, 7077888}};
  int z = blockIdx.z;
  int K = tab[z].K, N = tab[z].N;
  int n0 = blockIdx.x << 5, k0 = blockIdx.y << 5;
  if (n0 >= N || k0 >= K) return;
  const float* src;
  switch (z) {
    case 0: src = p0; break;  case 1: src = p1; break;
    case 2: src = p2; break;  case 3: src = p3; break;
    case 4: src = p4; break;  case 5: src = p5; break;
    case 6: src = p6; break;  case 7: src = p7; break;
    case 8: src = p8; break;  case 9: src = p9; break;
    case 10: src = p10; break; case 11: src = p11; break;
    case 12: src = p12; break; case 13: src = p13; break;
    case 14: src = p14; break; case 15: src = p15; break;
    case 16: src = p16; break; default: src = p17; break;
  }
  short* dst = wsb + tab[z].dst;
  __shared__ float tile[32][33];
  int tx = threadIdx.x, ty = threadIdx.y;
#pragma unroll
  for (int j = 0; j < 4; j++)
    tile[ty + j * 8][tx] = src[(long)(k0 + ty + j * 8) * N + n0 + tx];
  __syncthreads();
#pragma unroll
  for (int j = 0; j < 4; j++)
    dst[(long)(n0 + ty + j * 8) * K + k0 + tx] = f2bf(tile[tx][ty + j * 8]);
}

// biases + zt transpose (zt now bf16)
__global__ __launch_bounds__(256) void prep_misc(
    const float* __restrict__ zsrc, const float* __restrict__ ada_scale_b,
    const float* __restrict__ pb_q_b, const float* __restrict__ op_b,
    const float* __restrict__ tr_out_b, const float* __restrict__ tmp_q_b,
    const float* __restrict__ tr_scale_b,
    float* __restrict__ biasbuf, short* __restrict__ zt) {
  int idx = blockIdx.x * 256 + threadIdx.x;
  if (idx < 1572864) {
    int k = idx & 255, qq = (idx >> 8) & 255;
    int bh = idx >> 16;
    int h = bh % 12, b = bh / 12;
    zt[idx] = f2bf(zsrc[((long)(b * 256 + qq) * 256 + k) * 12 + h]);
  } else {
    int j = idx - 1572864;
    float v;
    if (j < 1536) v = (j < 768) ? ada_scale_b[j] : 0.f;
    else if (j < 4608) { int jj = j - 1536; v = (jj < 768) ? pb_q_b[jj] : 0.f; }
    else if (j < 6144) { int jj = j - 4608; v = (jj < 768) ? op_b[jj] : tr_out_b[jj - 768]; }
    else if (j < 8448) { int jj = j - 6144; v = (jj < 768) ? tmp_q_b[jj] : 0.f; }
    else { int jj = j - 8448; v = (jj < 768) ? tr_scale_b[jj] : 0.f; }
    biasbuf[j] = v;
  }
}

// ---------------------------------------------------------------------------
// LayerNorm kernels — wave-per-row (64 lanes x 12 elems), 4 rows/block,
// shuffle-only reduction: no LDS, no barrier.
// ---------------------------------------------------------------------------
__global__ __launch_bounds__(256) void ln_quad(
    const float* __restrict__ a, const float* __restrict__ s,
    const float* __restrict__ w1, const float* __restrict__ w2,
    short* __restrict__ an1, short* __restrict__ sn1, short* __restrict__ sn2,
    short* __restrict__ sbf) {
  const int wave = threadIdx.x >> 6, lane = threadIdx.x & 63;
  const int row = (blockIdx.x << 2) + wave;
  const float* ar = a + (long)row * 768;
  const float* sr = s + (long)row * 768;
  f32x4 av[3], sv[3];
  float s0 = 0, s1 = 0, s2 = 0, s3 = 0;
#pragma unroll
  for (int k = 0; k < 3; k++) {
    int col = (lane << 2) + (k << 8);
    av[k] = *(const f32x4*)(ar + col);
    sv[k] = *(const f32x4*)(sr + col);
#pragma unroll
    for (int e = 0; e < 4; e++) {
      s0 += av[k][e]; s1 += av[k][e] * av[k][e];
      s2 += sv[k][e]; s3 += sv[k][e] * sv[k][e];
    }
  }
#pragma unroll
  for (int o = 32; o; o >>= 1) {
    s0 += __shfl_xor(s0, o, 64); s1 += __shfl_xor(s1, o, 64);
    s2 += __shfl_xor(s2, o, 64); s3 += __shfl_xor(s3, o, 64);
  }
  const float inv768 = 1.f / 768.f;
  float ma = s0 * inv768, va = s1 * inv768 - ma * ma;
  float ia = rsqrtf(va + 1e-5f);
  float ms = s2 * inv768, vs = s3 * inv768 - ms * ms;
  float is_ = rsqrtf(vs + 1e-5f);
#pragma unroll
  for (int k = 0; k < 3; k++) {
    int col = (lane << 2) + (k << 8);
    long o = (long)row * 768 + col;
    s16x4 o1, o2, o3, o4;
#pragma unroll
    for (int e = 0; e < 4; e++) {
      o1[e] = f2bf((av[k][e] - ma) * ia);
      float sn = (sv[k][e] - ms) * is_;
      o2[e] = f2bf(sn * w1[col + e]);
      o3[e] = f2bf(sn * w2[col + e]);
      o4[e] = f2bf(sv[k][e]);
    }
    *(s16x4*)(an1 + o) = o1;
    *(s16x4*)(sn1 + o) = o2;
    *(s16x4*)(sn2 + o) = o3;
    *(s16x4*)(sbf + o) = o4;
  }
}

__global__ __launch_bounds__(256) void ln_affine(
    const float* __restrict__ in, const float* __restrict__ w,
    const float* __restrict__ b, short* __restrict__ out) {
  const int wave = threadIdx.x >> 6, lane = threadIdx.x & 63;
  const int row = (blockIdx.x << 2) + wave;
  const float* xr = in + (long)row * 768;
  f32x4 xv[3];
  float s0 = 0, s1 = 0;
#pragma unroll
  for (int k = 0; k < 3; k++) {
    int col = (lane << 2) + (k << 8);
    xv[k] = *(const f32x4*)(xr + col);
#pragma unroll
    for (int e = 0; e < 4; e++) { s0 += xv[k][e]; s1 += xv[k][e] * xv[k][e]; }
  }
#pragma unroll
  for (int o = 32; o; o >>= 1) { s0 += __shfl_xor(s0, o, 64); s1 += __shfl_xor(s1, o, 64); }
  const float inv768 = 1.f / 768.f;
  float m = s0 * inv768, v = s1 * inv768 - m * m;
  float inv = rsqrtf(v + 1e-5f);
#pragma unroll
  for (int k = 0; k < 3; k++) {
    int col = (lane << 2) + (k << 8);
    s16x4 p;
#pragma unroll
    for (int e = 0; e < 4; e++) {
      float y = (xv[k][e] - m) * inv;
      if (w) y = y * w[col + e] + b[col + e];
      p[e] = f2bf(y);
    }
    *(s16x4*)(out + (long)row * 768 + col) = p;
  }
}

// ---------------------------------------------------------------------------
// Generic bf16 GEMM, C[M][N] = A[M][K] @ W[N][K]^T.
// Single-barrier LDS double-buffer K-loop: barrier -> issue prefetch of tile
// k+1 into the other buffer -> compute tile k. The vmcnt(0) drain at the NEXT
// barrier waits on loads that flew during this iter's compute.
// EP: 0 = bf16(+bias), 1 = bf16 sigmoid(+bias), 2 = f32 res+acc, 3 = f32 res+gate*acc
// ---------------------------------------------------------------------------
__device__ __forceinline__ void stage_bt(
    const short* __restrict__ A, const short* __restrict__ W,
    short* sa, short* sb, int m0, int n0, int ldA, int K, int kt,
    int tid, int wave) {
#pragma unroll
  for (int t = 0; t < 4; t++) {
    int c = (t << 8) + tid;
    int m = c >> 3, kc = (c & 7) ^ (m & 7);
    gl2lds16(A + (long)(m0 + m) * ldA + kt + (kc << 3),
             sa + (((t << 8) + (wave << 6)) << 3));
    gl2lds16(W + (long)(n0 + m) * K + kt + (kc << 3),
             sb + (((t << 8) + (wave << 6)) << 3));
  }
}

template <int EP>
__global__ __launch_bounds__(256) void gemm_bt(
    const short* __restrict__ A, const short* __restrict__ W,
    const float* __restrict__ bias, void* __restrict__ Cout,
    const float* __restrict__ res, const short* __restrict__ gate,
    int K, int ldA, int ldC, int gld) {
  __shared__ short sA[2][128 * 64];
  __shared__ short sB[2][128 * 64];
  const int tid = threadIdx.x;
  const int wave = tid >> 6, lane = tid & 63;
  const int m0 = blockIdx.y << 7;
  const int n0 = blockIdx.x << 7;
  const int wm = (wave & 1) << 6, wn = (wave >> 1) << 6;
  const int q = lane >> 4, r = lane & 15;
  f32x4 acc[4][4];
#pragma unroll
  for (int i = 0; i < 4; i++)
#pragma unroll
    for (int j = 0; j < 4; j++) acc[i][j] = (f32x4){0.f, 0.f, 0.f, 0.f};

  stage_bt(A, W, sA[0], sB[0], m0, n0, ldA, K, 0, tid, wave);
  const int nk = K >> 6;
  for (int ki = 0; ki < nk; ki++) {
    __syncthreads();  // drains vmcnt(0): buffer ki ready
    if (ki + 1 < nk)
      stage_bt(A, W, sA[(ki + 1) & 1], sB[(ki + 1) & 1], m0, n0, ldA, K,
               (ki + 1) << 6, tid, wave);
    const short* cA = sA[ki & 1];
    const short* cB = sB[ki & 1];
#pragma unroll
    for (int ks = 0; ks < 2; ks++) {
      s16x8 av[4], bv[4];
#pragma unroll
      for (int mt = 0; mt < 4; mt++) {
        int row = wm + (mt << 4) + r;
        int ch = ((ks << 2) + q) ^ (row & 7);
        av[mt] = *(const s16x8*)(cA + ((row << 3) + ch) * 8);
      }
#pragma unroll
      for (int nt = 0; nt < 4; nt++) {
        int row = wn + (nt << 4) + r;
        int ch = ((ks << 2) + q) ^ (row & 7);
        bv[nt] = *(const s16x8*)(cB + ((row << 3) + ch) * 8);
      }
#pragma unroll
      for (int mt = 0; mt < 4; mt++)
#pragma unroll
        for (int nt = 0; nt < 4; nt++)
          acc[mt][nt] = MFMA16(bv[nt], av[mt], acc[mt][nt]);  // swapped operands
    }
  }
  // Epilogue: lane holds row gm, 4 consecutive cols gnb..gnb+3
#pragma unroll
  for (int mt = 0; mt < 4; mt++) {
    const int gm = m0 + wm + (mt << 4) + r;
#pragma unroll
    for (int nt = 0; nt < 4; nt++) {
      const int gnb = n0 + wn + (nt << 4) + (q << 2);
      f32x4 v = acc[mt][nt];
      if (bias) {
        f32x4 b4 = *(const f32x4*)(bias + gnb);
        v += b4;
      }
      long o = (long)gm * ldC + gnb;
      if (EP == 0) {
        s16x4 p;
#pragma unroll
        for (int e = 0; e < 4; e++) p[e] = f2bf(v[e]);
        *(s16x4*)((short*)Cout + o) = p;
      } else if (EP == 1) {
        s16x4 p;
#pragma unroll
        for (int e = 0; e < 4; e++) p[e] = f2bf(sigmoidf_(v[e]));
        *(s16x4*)((short*)Cout + o) = p;
      } else if (EP == 2) {
        f32x4 r4 = *(const f32x4*)(res + o);
        *(f32x4*)((float*)Cout + o) = r4 + v;
      } else {
        f32x4 r4 = *(const f32x4*)(res + o);
        s16x4 g4 = *(const s16x4*)(gate + (long)gm * gld + gnb);
        f32x4 out;
#pragma unroll
        for (int e = 0; e < 4; e++) out[e] = r4[e] + bf2f(g4[e]) * v[e];
        *(f32x4*)((float*)Cout + o) = out;
      }
    }
  }
}

// ---------------------------------------------------------------------------
// Dual GEMM + fused combine, same single-barrier dbuf structure.
// MODE 0 (adaln): out = bf16( sigmoid(c1 + bias) * an + c2 ), ld 768
// MODE 1 (swiglu): out = bf16( silu(c1) * c2 ), ld 1536
// ---------------------------------------------------------------------------
__device__ __forceinline__ void stage_dual(
    const short* __restrict__ A, const short* __restrict__ W, int woff2,
    short* sa, short* sb1, short* sb2, int m0, int n0, int kt,
    int tid, int wave) {
#pragma unroll
  for (int t = 0; t < 4; t++) {
    int c = (t << 8) + tid;
    int m = c >> 3, kc = (c & 7) ^ (m & 7);
    gl2lds16(A + (long)(m0 + m) * 768 + kt + (kc << 3),
             sa + (((t << 8) + (wave << 6)) << 3));
  }
#pragma unroll
  for (int t = 0; t < 2; t++) {
    int c = (t << 8) + tid;
    int rb = c >> 3, kc = (c & 7) ^ (rb & 7);
    gl2lds16(W + (long)(n0 + rb) * 768 + kt + (kc << 3),
             sb1 + (((t << 8) + (wave << 6)) << 3));
    gl2lds16(W + (long)(woff2 + n0 + rb) * 768 + kt + (kc << 3),
             sb2 + (((t << 8) + (wave << 6)) << 3));
  }
}

template <int MODE>
__global__ __launch_bounds__(256) void gemm_dual(
    const short* __restrict__ A, const short* __restrict__ W, int woff2,
    const float* __restrict__ bias, const short* __restrict__ an,
    short* __restrict__ out, int ldO) {
  __shared__ short sA[2][128 * 64];
  __shared__ short sB1[2][64 * 64];
  __shared__ short sB2[2][64 * 64];
  const int tid = threadIdx.x;
  const int wave = tid >> 6, lane = tid & 63;
  const int m0 = blockIdx.y << 7;
  const int n0 = blockIdx.x << 6;
  const int wm = (wave & 1) << 6, wn = (wave >> 1) << 5;
  const int q = lane >> 4, r = lane & 15;
  f32x4 acc1[4][2], acc2[4][2];
#pragma unroll
  for (int i = 0; i < 4; i++)
#pragma unroll
    for (int j = 0; j < 2; j++) {
      acc1[i][j] = (f32x4){0.f, 0.f, 0.f, 0.f};
      acc2[i][j] = (f32x4){0.f, 0.f, 0.f, 0.f};
    }

  stage_dual(A, W, woff2, sA[0], sB1[0], sB2[0], m0, n0, 0, tid, wave);
  for (int ki = 0; ki < 12; ki++) {
    __syncthreads();
    if (ki + 1 < 12)
      stage_dual(A, W, woff2, sA[(ki + 1) & 1], sB1[(ki + 1) & 1],
                 sB2[(ki + 1) & 1], m0, n0, (ki + 1) << 6, tid, wave);
    const short* cA = sA[ki & 1];
    const short* cB1 = sB1[ki & 1];
    const short* cB2 = sB2[ki & 1];
#pragma unroll
    for (int ks = 0; ks < 2; ks++) {
      s16x8 av[4], b1[2], b2[2];
#pragma unroll
      for (int mt = 0; mt < 4; mt++) {
        int row = wm + (mt << 4) + r;
        int ch = ((ks << 2) + q) ^ (row & 7);
        av[mt] = *(const s16x8*)(cA + ((row << 3) + ch) * 8);
      }
#pragma unroll
      for (int nt = 0; nt < 2; nt++) {
        int row = wn + (nt << 4) + r;
        int ch = ((ks << 2) + q) ^ (row & 7);
        b1[nt] = *(const s16x8*)(cB1 + ((row << 3) + ch) * 8);
        b2[nt] = *(const s16x8*)(cB2 + ((row << 3) + ch) * 8);
      }
#pragma unroll
      for (int mt = 0; mt < 4; mt++)
#pragma unroll
        for (int nt = 0; nt < 2; nt++) {
          acc1[mt][nt] = MFMA16(b1[nt], av[mt], acc1[mt][nt]);
          acc2[mt][nt] = MFMA16(b2[nt], av[mt], acc2[mt][nt]);
        }
    }
  }
#pragma unroll
  for (int mt = 0; mt < 4; mt++) {
    const int gm = m0 + wm + (mt << 4) + r;
#pragma unroll
    for (int nt = 0; nt < 2; nt++) {
      const int gnb = n0 + wn + (nt << 4) + (q << 2);
      s16x4 p;
      if (MODE == 0) {
        f32x4 b4 = *(const f32x4*)(bias + gnb);
        s16x4 an4 = *(const s16x4*)(an + (long)gm * 768 + gnb);
#pragma unroll
        for (int e = 0; e < 4; e++)
          p[e] = f2bf(sigmoidf_(acc1[mt][nt][e] + b4[e]) * bf2f(an4[e]) +
                      acc2[mt][nt][e]);
      } else {
#pragma unroll
        for (int e = 0; e < 4; e++) {
          float x = acc1[mt][nt][e];
          p[e] = f2bf(x * sigmoidf_(x) * acc2[mt][nt][e]);
        }
      }
      *(s16x4*)(out + (long)gm * ldO + gnb) = p;
    }
  }
}

// ---------------------------------------------------------------------------
// Spatial attention: block per (qtile64, h, bt). MFMA QK^T + softmax + MFMA PV.
// zt bias is bf16 now.
// ---------------------------------------------------------------------------
__global__ __launch_bounds__(256) void attn_spatial(
    const short* __restrict__ qkvg, const short* __restrict__ zt, short* __restrict__ ogo) {
  __shared__ short sKP[256 * 64];  // K tile, later P
  __shared__ short sVt[64 * 256];  // V^T [d][tok]
  const int tid = threadIdx.x;
  const int wave = tid >> 6, lane = tid & 63;
  const int qt = blockIdx.x, h = blockIdx.y, bt = blockIdx.z;
  const int b = bt >> 4;
  const int q0 = qt << 6;
  const long rowbase = (long)bt << 8;
  const int hoff = h << 6;

#pragma unroll
  for (int t = 0; t < 8; t++) {  // K stage (swizzled)
    int c = (t << 8) + tid;
    int tok = c >> 3, kc = (c & 7) ^ (tok & 7);
    *(s16x8*)(sKP + (c << 3)) =
        *(const s16x8*)(qkvg + (rowbase + tok) * 3072 + 768 + hoff + (kc << 3));
  }
#pragma unroll
  for (int t = 0; t < 8; t++) {  // V^T stage
    int u = (t << 8) + tid;
    int tok = u >> 3, dc = u & 7;
    s16x8 v8 = *(const s16x8*)(qkvg + (rowbase + tok) * 3072 + 1536 + hoff + (dc << 3));
#pragma unroll
    for (int e = 0; e < 8; e++) {
      int d = (dc << 3) + e;
      int ch = (tok >> 3) ^ (d & 7);
      sVt[((d << 5) + ch) * 8 + (tok & 7)] = v8[e];
    }
  }
  __syncthreads();

  const int q = lane >> 4, cc = lane & 15;
  f32x4 acc[16];
#pragma unroll
  for (int i = 0; i < 16; i++) acc[i] = (f32x4){0.f, 0.f, 0.f, 0.f};
  {
    const int arow = (wave << 4) + cc;
    const short* qrow = qkvg + (rowbase + q0 + arow) * 3072 + hoff;
#pragma unroll
    for (int ks = 0; ks < 2; ks++) {
      s16x8 av = *(const s16x8*)(qrow + (ks << 5) + (q << 3));  // A frag from global
#pragma unroll
      for (int nt = 0; nt < 16; nt++) {
        int tok = (nt << 4) + cc;
        int chb = ((ks << 2) + q) ^ (tok & 7);
        s16x8 bv = *(const s16x8*)(sKP + ((tok << 3) + chb) * 8);
        acc[nt] = MFMA16(av, bv, acc[nt]);
      }
    }
  }
  // softmax (row = q0 + wave*16 + q*4 + reg, col = nt*16 + cc)
  const short* ztb = zt + (((long)(b * 12 + h) * 256 + q0 + (wave << 4)) << 8);
#pragma unroll
  for (int reg = 0; reg < 4; reg++) {
    int lr = (q << 2) + reg;
    float mx = -3.0e38f;
#pragma unroll
    for (int nt = 0; nt < 16; nt++) {
      float v = acc[nt][reg] * 0.125f + bf2f(ztb[lr * 256 + (nt << 4) + cc]);
      acc[nt][reg] = v;
      mx = fmaxf(mx, v);
    }
    mx = fmaxf(mx, __shfl_xor(mx, 1, 16));
    mx = fmaxf(mx, __shfl_xor(mx, 2, 16));
    mx = fmaxf(mx, __shfl_xor(mx, 4, 16));
    mx = fmaxf(mx, __shfl_xor(mx, 8, 16));
    float sum = 0.f;
#pragma unroll
    for (int nt = 0; nt < 16; nt++) {
      float e = __expf(acc[nt][reg] - mx);
      acc[nt][reg] = e; sum += e;
    }
    sum += __shfl_xor(sum, 1, 16);
    sum += __shfl_xor(sum, 2, 16);
    sum += __shfl_xor(sum, 4, 16);
    sum += __shfl_xor(sum, 8, 16);
    float inv = 1.f / sum;
#pragma unroll
    for (int nt = 0; nt < 16; nt++) acc[nt][reg] *= inv;
  }
  __syncthreads();  // everyone done reading K
#pragma unroll
  for (int nt = 0; nt < 16; nt++) {
#pragma unroll
    for (int reg = 0; reg < 4; reg++) {
      int rP = (wave << 4) + (q << 2) + reg;
      int col = (nt << 4) + cc;
      int ch = (col >> 3) ^ (rP & 7);
      sKP[((rP << 5) + ch) * 8 + (col & 7)] = f2bf(acc[nt][reg]);
    }
  }
  __syncthreads();
  // PV
  f32x4 oacc[4];
#pragma unroll
  for (int i = 0; i < 4; i++) oacc[i] = (f32x4){0.f, 0.f, 0.f, 0.f};
  const int prow = (wave << 4) + cc;
#pragma unroll
  for (int ksi = 0; ksi < 8; ksi++) {
    int cha = ((ksi << 2) + q) ^ (prow & 7);
    s16x8 pa = *(const s16x8*)(sKP + ((prow << 5) + cha) * 8);
#pragma unroll
    for (int dt = 0; dt < 4; dt++) {
      int d = (dt << 4) + cc;
      int chv = ((ksi << 2) + q) ^ (d & 7);
      s16x8 bv = *(const s16x8*)(sVt + ((d << 5) + chv) * 8);
      oacc[dt] = MFMA16(pa, bv, oacc[dt]);
    }
  }
#pragma unroll
  for (int dt = 0; dt < 4; dt++) {
#pragma unroll
    for (int reg = 0; reg < 4; reg++) {
      int rowt = q0 + (wave << 4) + (q << 2) + reg;
      int dcol = (dt << 4) + cc;
      long grow = rowbase + rowt;
      float gl = bf2f(qkvg[grow * 3072 + 2304 + hoff + dcol]);
      ogo[grow * 768 + hoff + dcol] = f2bf(oacc[dt][reg] * sigmoidf_(gl));
    }
  }
}

// ---------------------------------------------------------------------------
// Temporal attention: block per (b,n).
// ---------------------------------------------------------------------------
__global__ __launch_bounds__(256) void attn_temporal(
    const short* __restrict__ qkvt, const float* __restrict__ ts,
    const float* __restrict__ decay_raw, short* __restrict__ out) {
  __shared__ short sKV[16 * 1544];
  const int bn = blockIdx.x;
  const int b = bn >> 8, n = bn & 255;
  const int tid = threadIdx.x;
#pragma unroll
  for (int t = 0; t < 12; t++) {
    int u = t * 256 + tid;
    int row = u / 192, cc = u % 192;
    *(s16x8*)(sKV + row * 1544 + cc * 8) =
        *(const s16x8*)(qkvt + ((long)(b * 16 + row) * 256 + n) * 2304 + 768 + cc * 8);
  }
  __syncthreads();
  const int h = tid >> 4, tq = tid & 15;
  if (h < 12) {
    const int hoff = h << 6;
    float dec = log1pf(__expf(decay_raw[h]));
    float tsq = ts[b * 16 + tq];
    s16x8 qv[8];
    const short* qrow = qkvt + ((long)(b * 16 + tq) * 256 + n) * 2304 + hoff;
#pragma unroll
    for (int dc = 0; dc < 8; dc++) qv[dc] = *(const s16x8*)(qrow + dc * 8);
    float sc[16];
#pragma unroll
    for (int tk = 0; tk < 16; tk++) {
      float dot = 0.f;
#pragma unroll
      for (int dc = 0; dc < 8; dc++) {
        s16x8 kv = *(const s16x8*)(sKV + tk * 1544 + hoff + dc * 8);
#pragma unroll
        for (int e = 0; e < 8; e++) dot += bf2f(qv[dc][e]) * bf2f(kv[e]);
      }
      sc[tk] = dot * 0.125f - dec * fabsf(tsq - ts[b * 16 + tk]);
    }
    float mx = sc[0];
#pragma unroll
    for (int tk = 1; tk < 16; tk++) mx = fmaxf(mx, sc[tk]);
    float sum = 0.f;
#pragma unroll
    for (int tk = 0; tk < 16; tk++) { sc[tk] = __expf(sc[tk] - mx); sum += sc[tk]; }
    float inv = 1.f / sum;
    float oa[64];
#pragma unroll
    for (int d = 0; d < 64; d++) oa[d] = 0.f;
#pragma unroll
    for (int tk = 0; tk < 16; tk++) {
      float wgt = sc[tk] * inv;
#pragma unroll
      for (int dc = 0; dc < 8; dc++) {
        s16x8 vv = *(const s16x8*)(sKV + tk * 1544 + 768 + hoff + dc * 8);
#pragma unroll
        for (int e = 0; e < 8; e++) oa[dc * 8 + e] += wgt * bf2f(vv[e]);
      }
    }
    long orow = (long)(b * 16 + tq) * 256 + n;
#pragma unroll
    for (int dc = 0; dc < 8; dc++) {
      s16x8 o8;
#pragma unroll
      for (int e = 0; e < 8; e++) o8[e] = f2bf(oa[dc * 8 + e]);
      *(s16x8*)(out + orow * 768 + hoff + dc * 8) = o8;
    }
  }
}

// ---------------------------------------------------------------------------
// Host launcher
// ---------------------------------------------------------------------------
extern "C" void kernel_launch(void* const* d_in, const int* in_sizes, int n_in,
                              void* d_out, int out_size, void* d_ws, size_t ws_size,
                              hipStream_t stream) {
  (void)in_sizes; (void)n_in; (void)out_size; (void)ws_size;
  const float* a_in      = (const float*)d_in[0];
  const float* s_in      = (const float*)d_in[1];
  const float* bias_in   = (const float*)d_in[2];
  const float* ts        = (const float*)d_in[4];
  const float* ada_snorm = (const float*)d_in[7];
  const float* ada_scale_w = (const float*)d_in[8];
  const float* ada_scale_b = (const float*)d_in[9];
  const float* ada_shift_w = (const float*)d_in[10];
  const float* pb_q_w = (const float*)d_in[11];
  const float* pb_q_b = (const float*)d_in[12];
  const float* pb_k_w = (const float*)d_in[13];
  const float* pb_v_w = (const float*)d_in[14];
  const float* pb_g_w = (const float*)d_in[15];
  const float* pb_o_w = (const float*)d_in[16];
  const float* op_w = (const float*)d_in[17];
  const float* op_b = (const float*)d_in[18];
  const float* tr_snorm = (const float*)d_in[19];
  const float* tr_scale_w = (const float*)d_in[20];
  const float* tr_scale_b = (const float*)d_in[21];
  const float* tr_shift_w = (const float*)d_in[22];
  const float* tr_gate_w = (const float*)d_in[23];
  const float* tr_ab_w = (const float*)d_in[24];
  const float* tr_ba_w = (const float*)d_in[25];
  const float* tr_out_w = (const float*)d_in[26];
  const float* tr_out_b = (const float*)d_in[27];
  const float* tmp_ln_w = (const float*)d_in[28];
  const float* tmp_ln_b = (const float*)d_in[29];
  const float* tmp_q_w = (const float*)d_in[30];
  const float* tmp_q_b = (const float*)d_in[31];
  const float* tmp_k_w = (const float*)d_in[32];
  const float* tmp_v_w = (const float*)d_in[33];
  const float* tmp_decay = (const float*)d_in[34];
  const float* tmp_o_w = (const float*)d_in[35];

  char* ws = (char*)d_ws;
  short* W16 = (short*)ws;
  short* WADA1 = (short*)(ws + OFF_WADA1);
  short* WQKVG = (short*)(ws + OFF_WQKVG);
  short* WO = (short*)(ws + OFF_WO);
  short* WGATES = (short*)(ws + OFF_WGATES);
  short* WTMPQKV = (short*)(ws + OFF_WTMPQKV);
  short* WTMPO = (short*)(ws + OFF_WTMPO);
  short* WADA2 = (short*)(ws + OFF_WADA2);
  short* WTRANS = (short*)(ws + OFF_WTRANS);
  short* WBA = (short*)(ws + OFF_WBA);
  float* BIASB = (float*)(ws + OFF_BIAS);
  short* ZT = (short*)(ws + OFF_ZT);
  short* AN1 = (short*)(ws + OFF_AN1);
  short* SN1 = (short*)(ws + OFF_SN1);
  short* SN2 = (short*)(ws + OFF_SN2);
  short* SBF = (short*)(ws + OFF_SBF);
  short* CADA = (short*)(ws + OFF_CADA);
  short* QKVG = (short*)(ws + OFF_QKVG);
  short* GATES = (short*)(ws + OFF_GATES);
  short* OGO = (short*)(ws + OFF_OGO);
  float* A1F = (float*)(ws + OFF_A1);
  float* OUTF = (float*)d_out;

  // 1-2: prep
  prep_weights<<<dim3(48, 48, 18), dim3(32, 8, 1), 0, stream>>>(
      ada_scale_w, ada_shift_w, pb_q_w, pb_k_w, pb_v_w, pb_g_w, pb_o_w,
      op_w, tr_out_w, tr_scale_w, tr_shift_w, tr_gate_w, tr_ab_w, tr_ba_w,
      tmp_q_w, tmp_k_w, tmp_v_w, tmp_o_w, W16);
  prep_misc<<<6183, 256, 0, stream>>>(bias_in, ada_scale_b, pb_q_b, op_b,
                                      tr_out_b, tmp_q_b, tr_scale_b, BIASB, ZT);
  // 3: LN(a), LN(s)*w1, LN(s)*w2, bf16(s)
  ln_quad<<<2048, 256, 0, stream>>>(a_in, s_in, ada_snorm, tr_snorm, AN1, SN1, SN2, SBF);
  // 4: gates = sigmoid(s @ [op|tr_out] + b)
  gemm_bt<1><<<dim3(12, 64), 256, 0, stream>>>(SBF, WGATES, BIASB + 4608, GATES,
                                               nullptr, nullptr, 768, 768, 1536, 0);
  // 5: AdaLN #1 fused: b = sigmoid(sn@scale+b)*an + sn@shift  -> SBF
  gemm_dual<0><<<dim3(12, 64), 256, 0, stream>>>(SN1, WADA1, 768, BIASB + 0, AN1,
                                                 SBF, 768);
  // 6: qkvg
  gemm_bt<0><<<dim3(24, 64), 256, 0, stream>>>(SBF, WQKVG, BIASB + 1536, QKVG,
                                               nullptr, nullptr, 768, 768, 3072, 0);
  // 7: spatial attention (writes sigmoid(g)*o)
  attn_spatial<<<dim3(4, 12, 32), 256, 0, stream>>>(QKVG, ZT, OGO);
  // 8: a1 = a + gate_op * (go @ o_w)
  gemm_bt<3><<<dim3(6, 64), 256, 0, stream>>>(OGO, WO, nullptr, A1F, a_in, GATES,
                                              768, 768, 768, 1536);
  // 9: h = LN(a1)*w+b
  ln_affine<<<2048, 256, 0, stream>>>(A1F, tmp_ln_w, tmp_ln_b, AN1);
  // 10: temporal qkv
  gemm_bt<0><<<dim3(18, 64), 256, 0, stream>>>(AN1, WTMPQKV, BIASB + 6144, QKVG,
                                               nullptr, nullptr, 768, 768, 2304, 0);
  // 11: temporal attention
  attn_temporal<<<512, 256, 0, stream>>>(QKVG, ts, tmp_decay, OGO);
  // 12: a2 = a1 + tattn @ tmp_o_w   (in place)
  gemm_bt<2><<<dim3(6, 64), 256, 0, stream>>>(OGO, WTMPO, nullptr, A1F, A1F, nullptr,
                                              768, 768, 768, 0);
  // 13: an2 = LN(a2)
  ln_affine<<<2048, 256, 0, stream>>>(A1F, nullptr, nullptr, SN1);
  // 14: AdaLN #2 fused -> b2 in SBF
  gemm_dual<0><<<dim3(12, 64), 256, 0, stream>>>(SN2, WADA2, 768, BIASB + 8448, SN1,
                                                 SBF, 768);
  // 15: transition fused SwiGLU: hid = silu(b2@gate)*(b2@ab) -> CADA
  gemm_dual<1><<<dim3(24, 64), 256, 0, stream>>>(SBF, WTRANS, 1536, nullptr, nullptr,
                                                 CADA, 1536);
  // 16: out = a2 + gate_tr * (hid @ ba_w)
  gemm_bt<3><<<dim3(6, 64), 256, 0, stream>>>(CADA, WBA, nullptr, OUTF, A1F,
                                              GATES + 768, 1536, 1536, 768, 1536);
}

// Round 4
// 680.251 us; speedup vs baseline: 1.0277x; 1.0277x over previous
//
#include <hip/hip_runtime.h>

// ---------------------------------------------------------------------------
// Types / helpers
// ---------------------------------------------------------------------------
typedef short s16x8 __attribute__((ext_vector_type(8)));
typedef short s16x4 __attribute__((ext_vector_type(4)));
typedef float f32x4 __attribute__((ext_vector_type(4)));
typedef __bf16 bf16x8 __attribute__((ext_vector_type(8)));

__device__ __forceinline__ float bf2f(short u) {
  union { unsigned int i; float f; } c;
  c.i = ((unsigned int)(unsigned short)u) << 16;
  return c.f;
}
__device__ __forceinline__ short f2bf(float f) {
  union { float f; unsigned int i; } c; c.f = f;
  unsigned int r = c.i + 0x7FFFu + ((c.i >> 16) & 1u);  // RNE
  return (short)(r >> 16);
}
__device__ __forceinline__ float sigmoidf_(float x) { return 1.f / (1.f + __expf(-x)); }

template <typename T>
__device__ __forceinline__ auto mfma_sel(T a, T b, f32x4 c, int)
    -> decltype(__builtin_amdgcn_mfma_f32_16x16x32_bf16(a, b, c, 0, 0, 0)) {
  return __builtin_amdgcn_mfma_f32_16x16x32_bf16(a, b, c, 0, 0, 0);
}
template <typename T>
__device__ __forceinline__ f32x4 mfma_sel(T a, T b, f32x4 c, long) {
  return __builtin_amdgcn_mfma_f32_16x16x32_bf16(
      __builtin_bit_cast(bf16x8, a), __builtin_bit_cast(bf16x8, b), c, 0, 0, 0);
}
__device__ __forceinline__ f32x4 MFMA16(s16x8 a, s16x8 b, f32x4 c) {
  return mfma_sel(a, b, c, 0);
}

__device__ __forceinline__ void gl2lds16(const void* g, void* l) {
  __builtin_amdgcn_global_load_lds(
      (const __attribute__((address_space(1))) unsigned int*)g,
      (__attribute__((address_space(3))) unsigned int*)l, 16, 0, 0);
}

// ---------------------------------------------------------------------------
// Workspace layout (byte offsets)
// ---------------------------------------------------------------------------
#define OFF_WADA1    0u             // [1536][768] bf16 (scale^T | shift^T)
#define OFF_WQKVG    2359296u       // [3072][768] bf16 (q|k|v|g ^T)
#define OFF_WO       7077888u       // [768][768]
#define OFF_WGATES   8257536u       // [1536][768] (op^T | tr_out^T)
#define OFF_WTMPQKV  10616832u      // [2304][768]
#define OFF_WTMPO    14155776u      // [768][768]
#define OFF_WADA2    15335424u      // [1536][768]
#define OFF_WTRANS   17694720u      // [3072][768] (gate^T | ab^T)
#define OFF_WBA      22413312u      // [768][1536]
#define OFF_BIAS     24772608u      // 9984 floats
#define OFF_ZT       24812544u      // [2][12][256][256] bf16 (3 MB)
#define OFF_AN1      31104000u      // bf16 [8192][768]  (an1 / h)
#define OFF_SN1      43686912u      // bf16 [8192][768]  (sn1 / an2)
#define OFF_SN2      56269824u      // bf16 [8192][768]
#define OFF_SBF      68852736u      // bf16 [8192][768]  (s_bf / b_act / b2)
#define OFF_CADA     81435648u      // bf16 [8192][1536] (hid)
#define OFF_QKVG     106601472u     // bf16 [8192][3072] (qkvg / qkvt)
#define OFF_GATES    156933120u     // bf16 [8192][1536] (sigmoid gates: op | tr)
#define OFF_OGO      182098944u     // bf16 [8192][768]  (gated attn out / tattn)
#define OFF_A1       194681856u     // f32  [8192][768]  (a1, then a2 in-place)

// ---------------------------------------------------------------------------
// Mega prep kernel: z<18 weight transpose; z=18 zt transpose (coalesced) +
// bias assembly; z=19 ln_quad. Block dims (32,8).
// ---------------------------------------------------------------------------
__global__ __launch_bounds__(256) void prep_all(
    const float* p0, const float* p1, const float* p2, const float* p3,
    const float* p4, const float* p5, const float* p6, const float* p7,
    const float* p8, const float* p9, const float* p10, const float* p11,
    const float* p12, const float* p13, const float* p14, const float* p15,
    const float* p16, const float* p17, short* wsb,
    const float* __restrict__ zsrc, const float* __restrict__ ada_scale_b,
    const float* __restrict__ pb_q_b, const float* __restrict__ op_b,
    const float* __restrict__ tr_out_b, const float* __restrict__ tmp_q_b,
    const float* __restrict__ tr_scale_b,
    float* __restrict__ biasbuf, short* __restrict__ zt,
    const float* __restrict__ a_in, const float* __restrict__ s_in,
    const float* __restrict__ lnw1, const float* __restrict__ lnw2,
    short* __restrict__ an1, short* __restrict__ sn1, short* __restrict__ sn2,
    short* __restrict__ sbf) {
  const int z = blockIdx.z;
  const int tid = threadIdx.y * 32 + threadIdx.x;
  if (z < 18) {
    // ---- weight transpose fp32 [K][N] -> bf16 [N][K] ----
    struct E { int K, N, dst; };
    const E tab[18] = {
        {768, 768, 0},        {768, 768, 589824},
        {768, 768, 1179648},  {768, 768, 1769472},
        {768, 768, 2359296},  {768, 768, 2949120},
        {768, 768, 3538944},
        {768, 768, 4128768},  {768, 768, 4718592},
        {768, 768, 7667712},  {768, 768, 8257536},
        {768, 1536, 8847360}, {768, 1536, 10027008},
        {1536, 768, 11206656},
        {768, 768, 5308416},  {768, 768, 5898240}, {768, 768, 6488064},
        {768, 768, 7077888}};
    int K = tab[z].K, N = tab[z].N;
    int n0 = blockIdx.x << 5, k0 = blockIdx.y << 5;
    if (n0 >= N || k0 >= K) return;
    const float* src;
    switch (z) {
      case 0: src = p0; break;  case 1: src = p1; break;
      case 2: src = p2; break;  case 3: src = p3; break;
      case 4: src = p4; break;  case 5: src = p5; break;
      case 6: src = p6; break;  case 7: src = p7; break;
      case 8: src = p8; break;  case 9: src = p9; break;
      case 10: src = p10; break; case 11: src = p11; break;
      case 12: src = p12; break; case 13: src = p13; break;
      case 14: src = p14; break; case 15: src = p15; break;
      case 16: src = p16; break; default: src = p17; break;
    }
    short* dst = wsb + tab[z].dst;
    __shared__ float tile[32][33];
    int tx = threadIdx.x, ty = threadIdx.y;
#pragma unroll
    for (int j = 0; j < 4; j++)
      tile[ty + j * 8][tx] = src[(long)(k0 + ty + j * 8) * N + n0 + tx];
    __syncthreads();
#pragma unroll
    for (int j = 0; j < 4; j++)
      dst[(long)(n0 + ty + j * 8) * K + k0 + tx] = f2bf(tile[tx][ty + j * 8]);
  } else if (z == 18) {
    const int bid = blockIdx.y * 48 + blockIdx.x;
    if (bid < 512) {
      // zt transpose, coalesced: block = (b,q); reads 12 contiguous floats/thread
      const int b = bid >> 8, qq = bid & 255;
      const float* src = zsrc + (long)bid * 3072 + tid * 12;
      f32x4 v0 = *(const f32x4*)(src);
      f32x4 v1 = *(const f32x4*)(src + 4);
      f32x4 v2 = *(const f32x4*)(src + 8);
      float vals[12] = {v0[0], v0[1], v0[2], v0[3], v1[0], v1[1],
                        v1[2], v1[3], v2[0], v2[1], v2[2], v2[3]};
#pragma unroll
      for (int h = 0; h < 12; h++)
        zt[(((long)(b * 12 + h) * 256 + qq) << 8) + tid] = f2bf(vals[h]);
    } else if (bid < 551) {
      int j = (bid - 512) * 256 + tid;
      if (j < 9984) {
        float v;
        if (j < 1536) v = (j < 768) ? ada_scale_b[j] : 0.f;
        else if (j < 4608) { int jj = j - 1536; v = (jj < 768) ? pb_q_b[jj] : 0.f; }
        else if (j < 6144) { int jj = j - 4608; v = (jj < 768) ? op_b[jj] : tr_out_b[jj - 768]; }
        else if (j < 8448) { int jj = j - 6144; v = (jj < 768) ? tmp_q_b[jj] : 0.f; }
        else { int jj = j - 8448; v = (jj < 768) ? tr_scale_b[jj] : 0.f; }
        biasbuf[j] = v;
      }
    }
  } else {
    // ---- ln_quad: wave-per-row, 4 rows per block ----
    const int bid = blockIdx.y * 48 + blockIdx.x;
    if (bid >= 2048) return;
    const int wave = tid >> 6, lane = tid & 63;
    const int row = (bid << 2) + wave;
    const float* ar = a_in + (long)row * 768;
    const float* sr = s_in + (long)row * 768;
    f32x4 av[3], sv[3];
    float s0 = 0, s1 = 0, s2 = 0, s3 = 0;
#pragma unroll
    for (int k = 0; k < 3; k++) {
      int col = (lane << 2) + (k << 8);
      av[k] = *(const f32x4*)(ar + col);
      sv[k] = *(const f32x4*)(sr + col);
#pragma unroll
      for (int e = 0; e < 4; e++) {
        s0 += av[k][e]; s1 += av[k][e] * av[k][e];
        s2 += sv[k][e]; s3 += sv[k][e] * sv[k][e];
      }
    }
#pragma unroll
    for (int o = 32; o; o >>= 1) {
      s0 += __shfl_xor(s0, o, 64); s1 += __shfl_xor(s1, o, 64);
      s2 += __shfl_xor(s2, o, 64); s3 += __shfl_xor(s3, o, 64);
    }
    const float inv768 = 1.f / 768.f;
    float ma = s0 * inv768, va = s1 * inv768 - ma * ma;
    float ia = rsqrtf(va + 1e-5f);
    float ms = s2 * inv768, vs = s3 * inv768 - ms * ms;
    float is_ = rsqrtf(vs + 1e-5f);
#pragma unroll
    for (int k = 0; k < 3; k++) {
      int col = (lane << 2) + (k << 8);
      long o = (long)row * 768 + col;
      s16x4 o1, o2, o3, o4;
#pragma unroll
      for (int e = 0; e < 4; e++) {
        o1[e] = f2bf((av[k][e] - ma) * ia);
        float sn = (sv[k][e] - ms) * is_;
        o2[e] = f2bf(sn * lnw1[col + e]);
        o3[e] = f2bf(sn * lnw2[col + e]);
        o4[e] = f2bf(sv[k][e]);
      }
      *(s16x4*)(an1 + o) = o1;
      *(s16x4*)(sn1 + o) = o2;
      *(s16x4*)(sn2 + o) = o3;
      *(s16x4*)(sbf + o) = o4;
    }
  }
}

// ---------------------------------------------------------------------------
// ln_affine (standalone): wave-per-row, 4 rows/block
// ---------------------------------------------------------------------------
__global__ __launch_bounds__(256) void ln_affine(
    const float* __restrict__ in, const float* __restrict__ w,
    const float* __restrict__ b, short* __restrict__ out) {
  const int wave = threadIdx.x >> 6, lane = threadIdx.x & 63;
  const int row = (blockIdx.x << 2) + wave;
  const float* xr = in + (long)row * 768;
  f32x4 xv[3];
  float s0 = 0, s1 = 0;
#pragma unroll
  for (int k = 0; k < 3; k++) {
    int col = (lane << 2) + (k << 8);
    xv[k] = *(const f32x4*)(xr + col);
#pragma unroll
    for (int e = 0; e < 4; e++) { s0 += xv[k][e]; s1 += xv[k][e] * xv[k][e]; }
  }
#pragma unroll
  for (int o = 32; o; o >>= 1) { s0 += __shfl_xor(s0, o, 64); s1 += __shfl_xor(s1, o, 64); }
  const float inv768 = 1.f / 768.f;
  float m = s0 * inv768, v = s1 * inv768 - m * m;
  float inv = rsqrtf(v + 1e-5f);
#pragma unroll
  for (int k = 0; k < 3; k++) {
    int col = (lane << 2) + (k << 8);
    s16x4 p;
#pragma unroll
    for (int e = 0; e < 4; e++) {
      float y = (xv[k][e] - m) * inv;
      if (w) y = y * w[col + e] + b[col + e];
      p[e] = f2bf(y);
    }
    *(s16x4*)(out + (long)row * 768 + col) = p;
  }
}

// ---------------------------------------------------------------------------
// GEMM engine (round-2 proven bodies), as device functions over a 32 KB LDS.
// C[M][N] = A[M][K] @ W[N][K]^T; operand-swapped MFMA -> vectorized epilogue.
// EP: 0 bf16(+bias), 1 bf16 sigmoid(+bias), 2 f32 res+acc, 3 f32 res+gate*acc
// ---------------------------------------------------------------------------
template <int EP>
__device__ __forceinline__ void dev_gemm_bt(
    short* lds,
    const short* __restrict__ A, const short* __restrict__ W,
    const float* __restrict__ bias, void* __restrict__ Cout,
    const float* __restrict__ res, const short* __restrict__ gate,
    int K, int ldA, int ldC, int gld) {
  short* sA = lds;
  short* sB = lds + 8192;
  const int tid = threadIdx.x;
  const int wave = tid >> 6, lane = tid & 63;
  const int m0 = blockIdx.y << 7;
  const int n0 = blockIdx.x << 7;
  const int wm = (wave & 1) << 6, wn = (wave >> 1) << 6;
  const int q = lane >> 4, r = lane & 15;
  f32x4 acc[4][4];
#pragma unroll
  for (int i = 0; i < 4; i++)
#pragma unroll
    for (int j = 0; j < 4; j++) acc[i][j] = (f32x4){0.f, 0.f, 0.f, 0.f};

  for (int kt = 0; kt < K; kt += 64) {
    __syncthreads();
#pragma unroll
    for (int t = 0; t < 4; t++) {
      int c = (t << 8) + tid;
      int m = c >> 3, kc = (c & 7) ^ (m & 7);
      gl2lds16(A + (long)(m0 + m) * ldA + kt + (kc << 3),
               sA + (((t << 8) + (wave << 6)) << 3));
      gl2lds16(W + (long)(n0 + m) * K + kt + (kc << 3),
               sB + (((t << 8) + (wave << 6)) << 3));
    }
    __syncthreads();
#pragma unroll
    for (int ks = 0; ks < 2; ks++) {
      s16x8 av[4], bv[4];
#pragma unroll
      for (int mt = 0; mt < 4; mt++) {
        int row = wm + (mt << 4) + r;
        int ch = ((ks << 2) + q) ^ (row & 7);
        av[mt] = *(const s16x8*)(sA + ((row << 3) + ch) * 8);
      }
#pragma unroll
      for (int nt = 0; nt < 4; nt++) {
        int row = wn + (nt << 4) + r;
        int ch = ((ks << 2) + q) ^ (row & 7);
        bv[nt] = *(const s16x8*)(sB + ((row << 3) + ch) * 8);
      }
#pragma unroll
      for (int mt = 0; mt < 4; mt++)
#pragma unroll
        for (int nt = 0; nt < 4; nt++)
          acc[mt][nt] = MFMA16(bv[nt], av[mt], acc[mt][nt]);  // swapped
    }
  }
#pragma unroll
  for (int mt = 0; mt < 4; mt++) {
    const int gm = m0 + wm + (mt << 4) + r;
#pragma unroll
    for (int nt = 0; nt < 4; nt++) {
      const int gnb = n0 + wn + (nt << 4) + (q << 2);
      f32x4 v = acc[mt][nt];
      if (bias) {
        f32x4 b4 = *(const f32x4*)(bias + gnb);
        v += b4;
      }
      long o = (long)gm * ldC + gnb;
      if (EP == 0) {
        s16x4 p;
#pragma unroll
        for (int e = 0; e < 4; e++) p[e] = f2bf(v[e]);
        *(s16x4*)((short*)Cout + o) = p;
      } else if (EP == 1) {
        s16x4 p;
#pragma unroll
        for (int e = 0; e < 4; e++) p[e] = f2bf(sigmoidf_(v[e]));
        *(s16x4*)((short*)Cout + o) = p;
      } else if (EP == 2) {
        f32x4 r4 = *(const f32x4*)(res + o);
        *(f32x4*)((float*)Cout + o) = r4 + v;
      } else {
        f32x4 r4 = *(const f32x4*)(res + o);
        s16x4 g4 = *(const s16x4*)(gate + (long)gm * gld + gnb);
        f32x4 out;
#pragma unroll
        for (int e = 0; e < 4; e++) out[e] = r4[e] + bf2f(g4[e]) * v[e];
        *(f32x4*)((float*)Cout + o) = out;
      }
    }
  }
}

// Dual GEMM + fused combine (128x64 tile of both W halves).
// MODE 0 (adaln): out = bf16( sigmoid(c1+bias)*an + c2 ); MODE 1: silu(c1)*c2
template <int MODE>
__device__ __forceinline__ void dev_gemm_dual(
    short* lds,
    const short* __restrict__ A, const short* __restrict__ W, int woff2,
    const float* __restrict__ bias, const short* __restrict__ an,
    short* __restrict__ out, int ldO) {
  short* sA = lds;            // 8192 shorts
  short* sB1 = lds + 8192;    // 4096
  short* sB2 = lds + 12288;   // 4096
  const int tid = threadIdx.x;
  const int wave = tid >> 6, lane = tid & 63;
  const int m0 = blockIdx.y << 7;
  const int n0 = blockIdx.x << 6;
  const int wm = (wave & 1) << 6, wn = (wave >> 1) << 5;
  const int q = lane >> 4, r = lane & 15;
  f32x4 acc1[4][2], acc2[4][2];
#pragma unroll
  for (int i = 0; i < 4; i++)
#pragma unroll
    for (int j = 0; j < 2; j++) {
      acc1[i][j] = (f32x4){0.f, 0.f, 0.f, 0.f};
      acc2[i][j] = (f32x4){0.f, 0.f, 0.f, 0.f};
    }

  for (int kt = 0; kt < 768; kt += 64) {
    __syncthreads();
#pragma unroll
    for (int t = 0; t < 4; t++) {
      int c = (t << 8) + tid;
      int m = c >> 3, kc = (c & 7) ^ (m & 7);
      gl2lds16(A + (long)(m0 + m) * 768 + kt + (kc << 3),
               sA + (((t << 8) + (wave << 6)) << 3));
    }
#pragma unroll
    for (int t = 0; t < 2; t++) {
      int c = (t << 8) + tid;
      int rb = c >> 3, kc = (c & 7) ^ (rb & 7);
      gl2lds16(W + (long)(n0 + rb) * 768 + kt + (kc << 3),
               sB1 + (((t << 8) + (wave << 6)) << 3));
      gl2lds16(W + (long)(woff2 + n0 + rb) * 768 + kt + (kc << 3),
               sB2 + (((t << 8) + (wave << 6)) << 3));
    }
    __syncthreads();
#pragma unroll
    for (int ks = 0; ks < 2; ks++) {
      s16x8 av[4], b1[2], b2[2];
#pragma unroll
      for (int mt = 0; mt < 4; mt++) {
        int row = wm + (mt << 4) + r;
        int ch = ((ks << 2) + q) ^ (row & 7);
        av[mt] = *(const s16x8*)(sA + ((row << 3) + ch) * 8);
      }
#pragma unroll
      for (int nt = 0; nt < 2; nt++) {
        int row = wn + (nt << 4) + r;
        int ch = ((ks << 2) + q) ^ (row & 7);
        b1[nt] = *(const s16x8*)(sB1 + ((row << 3) + ch) * 8);
        b2[nt] = *(const s16x8*)(sB2 + ((row << 3) + ch) * 8);
      }
#pragma unroll
      for (int mt = 0; mt < 4; mt++)
#pragma unroll
        for (int nt = 0; nt < 2; nt++) {
          acc1[mt][nt] = MFMA16(b1[nt], av[mt], acc1[mt][nt]);
          acc2[mt][nt] = MFMA16(b2[nt], av[mt], acc2[mt][nt]);
        }
    }
  }
#pragma unroll
  for (int mt = 0; mt < 4; mt++) {
    const int gm = m0 + wm + (mt << 4) + r;
#pragma unroll
    for (int nt = 0; nt < 2; nt++) {
      const int gnb = n0 + wn + (nt << 4) + (q << 2);
      s16x4 p;
      if (MODE == 0) {
        f32x4 b4 = *(const f32x4*)(bias + gnb);
        s16x4 an4 = *(const s16x4*)(an + (long)gm * 768 + gnb);
#pragma unroll
        for (int e = 0; e < 4; e++)
          p[e] = f2bf(sigmoidf_(acc1[mt][nt][e] + b4[e]) * bf2f(an4[e]) +
                      acc2[mt][nt][e]);
      } else {
#pragma unroll
        for (int e = 0; e < 4; e++) {
          float x = acc1[mt][nt][e];
          p[e] = f2bf(x * sigmoidf_(x) * acc2[mt][nt][e]);
        }
      }
      *(s16x4*)(out + (long)gm * ldO + gnb) = p;
    }
  }
}

template <int EP>
__global__ __launch_bounds__(256) void gemm_bt(
    const short* __restrict__ A, const short* __restrict__ W,
    const float* __restrict__ bias, void* __restrict__ Cout,
    const float* __restrict__ res, const short* __restrict__ gate,
    int K, int ldA, int ldC, int gld) {
  __shared__ short lds[16384];
  dev_gemm_bt<EP>(lds, A, W, bias, Cout, res, gate, K, ldA, ldC, gld);
}

template <int MODE>
__global__ __launch_bounds__(256) void gemm_dual(
    const short* __restrict__ A, const short* __restrict__ W, int woff2,
    const float* __restrict__ bias, const short* __restrict__ an,
    short* __restrict__ out, int ldO) {
  __shared__ short lds[16384];
  dev_gemm_dual<MODE>(lds, A, W, woff2, bias, an, out, ldO);
}

// Fused independent pair: z=0 gates GEMM (sigmoid), z=1 AdaLN#1 dual.
__global__ __launch_bounds__(256) void gemm_pair(
    const short* __restrict__ sbf, const short* __restrict__ wgates,
    const float* __restrict__ bias_g, short* __restrict__ gates,
    const short* __restrict__ sn1, const short* __restrict__ wada1,
    const float* __restrict__ bias_a, const short* __restrict__ an1,
    short* __restrict__ outb) {
  __shared__ short lds[16384];
  if (blockIdx.z == 0)
    dev_gemm_bt<1>(lds, sbf, wgates, bias_g, (void*)gates, nullptr, nullptr,
                   768, 768, 1536, 0);
  else
    dev_gemm_dual<0>(lds, sn1, wada1, 768, bias_a, an1, outb, 768);
}

// ---------------------------------------------------------------------------
// Spatial attention: block per (qtile64, h, bt). MFMA QK^T + softmax + MFMA PV.
// ---------------------------------------------------------------------------
__global__ __launch_bounds__(256) void attn_spatial(
    const short* __restrict__ qkvg, const short* __restrict__ zt, short* __restrict__ ogo) {
  __shared__ short sKP[256 * 64];  // K tile, later P
  __shared__ short sVt[64 * 256];  // V^T [d][tok]
  const int tid = threadIdx.x;
  const int wave = tid >> 6, lane = tid & 63;
  const int qt = blockIdx.x, h = blockIdx.y, bt = blockIdx.z;
  const int b = bt >> 4;
  const int q0 = qt << 6;
  const long rowbase = (long)bt << 8;
  const int hoff = h << 6;

#pragma unroll
  for (int t = 0; t < 8; t++) {  // K stage (swizzled)
    int c = (t << 8) + tid;
    int tok = c >> 3, kc = (c & 7) ^ (tok & 7);
    *(s16x8*)(sKP + (c << 3)) =
        *(const s16x8*)(qkvg + (rowbase + tok) * 3072 + 768 + hoff + (kc << 3));
  }
#pragma unroll
  for (int t = 0; t < 8; t++) {  // V^T stage
    int u = (t << 8) + tid;
    int tok = u >> 3, dc = u & 7;
    s16x8 v8 = *(const s16x8*)(qkvg + (rowbase + tok) * 3072 + 1536 + hoff + (dc << 3));
#pragma unroll
    for (int e = 0; e < 8; e++) {
      int d = (dc << 3) + e;
      int ch = (tok >> 3) ^ (d & 7);
      sVt[((d << 5) + ch) * 8 + (tok & 7)] = v8[e];
    }
  }
  __syncthreads();

  const int q = lane >> 4, cc = lane & 15;
  f32x4 acc[16];
#pragma unroll
  for (int i = 0; i < 16; i++) acc[i] = (f32x4){0.f, 0.f, 0.f, 0.f};
  {
    const int arow = (wave << 4) + cc;
    const short* qrow = qkvg + (rowbase + q0 + arow) * 3072 + hoff;
#pragma unroll
    for (int ks = 0; ks < 2; ks++) {
      s16x8 av = *(const s16x8*)(qrow + (ks << 5) + (q << 3));
#pragma unroll
      for (int nt = 0; nt < 16; nt++) {
        int tok = (nt << 4) + cc;
        int chb = ((ks << 2) + q) ^ (tok & 7);
        s16x8 bv = *(const s16x8*)(sKP + ((tok << 3) + chb) * 8);
        acc[nt] = MFMA16(av, bv, acc[nt]);
      }
    }
  }
  const short* ztb = zt + (((long)(b * 12 + h) * 256 + q0 + (wave << 4)) << 8);
#pragma unroll
  for (int reg = 0; reg < 4; reg++) {
    int lr = (q << 2) + reg;
    float mx = -3.0e38f;
#pragma unroll
    for (int nt = 0; nt < 16; nt++) {
      float v = acc[nt][reg] * 0.125f + bf2f(ztb[lr * 256 + (nt << 4) + cc]);
      acc[nt][reg] = v;
      mx = fmaxf(mx, v);
    }
    mx = fmaxf(mx, __shfl_xor(mx, 1, 16));
    mx = fmaxf(mx, __shfl_xor(mx, 2, 16));
    mx = fmaxf(mx, __shfl_xor(mx, 4, 16));
    mx = fmaxf(mx, __shfl_xor(mx, 8, 16));
    float sum = 0.f;
#pragma unroll
    for (int nt = 0; nt < 16; nt++) {
      float e = __expf(acc[nt][reg] - mx);
      acc[nt][reg] = e; sum += e;
    }
    sum += __shfl_xor(sum, 1, 16);
    sum += __shfl_xor(sum, 2, 16);
    sum += __shfl_xor(sum, 4, 16);
    sum += __shfl_xor(sum, 8, 16);
    float inv = 1.f / sum;
#pragma unroll
    for (int nt = 0; nt < 16; nt++) acc[nt][reg] *= inv;
  }
  __syncthreads();
#pragma unroll
  for (int nt = 0; nt < 16; nt++) {
#pragma unroll
    for (int reg = 0; reg < 4; reg++) {
      int rP = (wave << 4) + (q << 2) + reg;
      int col = (nt << 4) + cc;
      int ch = (col >> 3) ^ (rP & 7);
      sKP[((rP << 5) + ch) * 8 + (col & 7)] = f2bf(acc[nt][reg]);
    }
  }
  __syncthreads();
  f32x4 oacc[4];
#pragma unroll
  for (int i = 0; i < 4; i++) oacc[i] = (f32x4){0.f, 0.f, 0.f, 0.f};
  const int prow = (wave << 4) + cc;
#pragma unroll
  for (int ksi = 0; ksi < 8; ksi++) {
    int cha = ((ksi << 2) + q) ^ (prow & 7);
    s16x8 pa = *(const s16x8*)(sKP + ((prow << 5) + cha) * 8);
#pragma unroll
    for (int dt = 0; dt < 4; dt++) {
      int d = (dt << 4) + cc;
      int chv = ((ksi << 2) + q) ^ (d & 7);
      s16x8 bv = *(const s16x8*)(sVt + ((d << 5) + chv) * 8);
      oacc[dt] = MFMA16(pa, bv, oacc[dt]);
    }
  }
#pragma unroll
  for (int dt = 0; dt < 4; dt++) {
#pragma unroll
    for (int reg = 0; reg < 4; reg++) {
      int rowt = q0 + (wave << 4) + (q << 2) + reg;
      int dcol = (dt << 4) + cc;
      long grow = rowbase + rowt;
      float gl = bf2f(qkvg[grow * 3072 + 2304 + hoff + dcol]);
      ogo[grow * 768 + hoff + dcol] = f2bf(oacc[dt][reg] * sigmoidf_(gl));
    }
  }
}

// ---------------------------------------------------------------------------
// Temporal attention: block per (b,n).
// ---------------------------------------------------------------------------
__global__ __launch_bounds__(256) void attn_temporal(
    const short* __restrict__ qkvt, const float* __restrict__ ts,
    const float* __restrict__ decay_raw, short* __restrict__ out) {
  __shared__ short sKV[16 * 1544];
  const int bn = blockIdx.x;
  const int b = bn >> 8, n = bn & 255;
  const int tid = threadIdx.x;
#pragma unroll
  for (int t = 0; t < 12; t++) {
    int u = t * 256 + tid;
    int row = u / 192, cc = u % 192;
    *(s16x8*)(sKV + row * 1544 + cc * 8) =
        *(const s16x8*)(qkvt + ((long)(b * 16 + row) * 256 + n) * 2304 + 768 + cc * 8);
  }
  __syncthreads();
  const int h = tid >> 4, tq = tid & 15;
  if (h < 12) {
    const int hoff = h << 6;
    float dec = log1pf(__expf(decay_raw[h]));
    float tsq = ts[b * 16 + tq];
    s16x8 qv[8];
    const short* qrow = qkvt + ((long)(b * 16 + tq) * 256 + n) * 2304 + hoff;
#pragma unroll
    for (int dc = 0; dc < 8; dc++) qv[dc] = *(const s16x8*)(qrow + dc * 8);
    float sc[16];
#pragma unroll
    for (int tk = 0; tk < 16; tk++) {
      float dot = 0.f;
#pragma unroll
      for (int dc = 0; dc < 8; dc++) {
        s16x8 kv = *(const s16x8*)(sKV + tk * 1544 + hoff + dc * 8);
#pragma unroll
        for (int e = 0; e < 8; e++) dot += bf2f(qv[dc][e]) * bf2f(kv[e]);
      }
      sc[tk] = dot * 0.125f - dec * fabsf(tsq - ts[b * 16 + tk]);
    }
    float mx = sc[0];
#pragma unroll
    for (int tk = 1; tk < 16; tk++) mx = fmaxf(mx, sc[tk]);
    float sum = 0.f;
#pragma unroll
    for (int tk = 0; tk < 16; tk++) { sc[tk] = __expf(sc[tk] - mx); sum += sc[tk]; }
    float inv = 1.f / sum;
    float oa[64];
#pragma unroll
    for (int d = 0; d < 64; d++) oa[d] = 0.f;
#pragma unroll
    for (int tk = 0; tk < 16; tk++) {
      float wgt = sc[tk] * inv;
#pragma unroll
      for (int dc = 0; dc < 8; dc++) {
        s16x8 vv = *(const s16x8*)(sKV + tk * 1544 + 768 + hoff + dc * 8);
#pragma unroll
        for (int e = 0; e < 8; e++) oa[dc * 8 + e] += wgt * bf2f(vv[e]);
      }
    }
    long orow = (long)(b * 16 + tq) * 256 + n;
#pragma unroll
    for (int dc = 0; dc < 8; dc++) {
      s16x8 o8;
#pragma unroll
      for (int e = 0; e < 8; e++) o8[e] = f2bf(oa[dc * 8 + e]);
      *(s16x8*)(out + orow * 768 + hoff + dc * 8) = o8;
    }
  }
}

// ---------------------------------------------------------------------------
// Host launcher
// ---------------------------------------------------------------------------
extern "C" void kernel_launch(void* const* d_in, const int* in_sizes, int n_in,
                              void* d_out, int out_size, void* d_ws, size_t ws_size,
                              hipStream_t stream) {
  (void)in_sizes; (void)n_in; (void)out_size; (void)ws_size;
  const float* a_in      = (const float*)d_in[0];
  const float* s_in      = (const float*)d_in[1];
  const float* bias_in   = (const float*)d_in[2];
  const float* ts        = (const float*)d_in[4];
  const float* ada_snorm = (const float*)d_in[7];
  const float* ada_scale_w = (const float*)d_in[8];
  const float* ada_scale_b = (const float*)d_in[9];
  const float* ada_shift_w = (const float*)d_in[10];
  const float* pb_q_w = (const float*)d_in[11];
  const float* pb_q_b = (const float*)d_in[12];
  const float* pb_k_w = (const float*)d_in[13];
  const float* pb_v_w = (const float*)d_in[14];
  const float* pb_g_w = (const float*)d_in[15];
  const float* pb_o_w = (const float*)d_in[16];
  const float* op_w = (const float*)d_in[17];
  const float* op_b = (const float*)d_in[18];
  const float* tr_snorm = (const float*)d_in[19];
  const float* tr_scale_w = (const float*)d_in[20];
  const float* tr_scale_b = (const float*)d_in[21];
  const float* tr_shift_w = (const float*)d_in[22];
  const float* tr_gate_w = (const float*)d_in[23];
  const float* tr_ab_w = (const float*)d_in[24];
  const float* tr_ba_w = (const float*)d_in[25];
  const float* tr_out_w = (const float*)d_in[26];
  const float* tr_out_b = (const float*)d_in[27];
  const float* tmp_ln_w = (const float*)d_in[28];
  const float* tmp_ln_b = (const float*)d_in[29];
  const float* tmp_q_w = (const float*)d_in[30];
  const float* tmp_q_b = (const float*)d_in[31];
  const float* tmp_k_w = (const float*)d_in[32];
  const float* tmp_v_w = (const float*)d_in[33];
  const float* tmp_decay = (const float*)d_in[34];
  const float* tmp_o_w = (const float*)d_in[35];

  char* ws = (char*)d_ws;
  short* W16 = (short*)ws;
  short* WADA1 = (short*)(ws + OFF_WADA1);
  short* WQKVG = (short*)(ws + OFF_WQKVG);
  short* WO = (short*)(ws + OFF_WO);
  short* WGATES = (short*)(ws + OFF_WGATES);
  short* WTMPQKV = (short*)(ws + OFF_WTMPQKV);
  short* WTMPO = (short*)(ws + OFF_WTMPO);
  short* WADA2 = (short*)(ws + OFF_WADA2);
  short* WTRANS = (short*)(ws + OFF_WTRANS);
  short* WBA = (short*)(ws + OFF_WBA);
  float* BIASB = (float*)(ws + OFF_BIAS);
  short* ZT = (short*)(ws + OFF_ZT);
  short* AN1 = (short*)(ws + OFF_AN1);
  short* SN1 = (short*)(ws + OFF_SN1);
  short* SN2 = (short*)(ws + OFF_SN2);
  short* SBF = (short*)(ws + OFF_SBF);
  short* CADA = (short*)(ws + OFF_CADA);
  short* QKVG = (short*)(ws + OFF_QKVG);
  short* GATES = (short*)(ws + OFF_GATES);
  short* OGO = (short*)(ws + OFF_OGO);
  float* A1F = (float*)(ws + OFF_A1);
  float* OUTF = (float*)d_out;

  // 1: all prep + ln_quad in one dispatch (z<18 weights, z=18 zt/bias, z=19 ln)
  prep_all<<<dim3(48, 48, 20), dim3(32, 8, 1), 0, stream>>>(
      ada_scale_w, ada_shift_w, pb_q_w, pb_k_w, pb_v_w, pb_g_w, pb_o_w,
      op_w, tr_out_w, tr_scale_w, tr_shift_w, tr_gate_w, tr_ab_w, tr_ba_w,
      tmp_q_w, tmp_k_w, tmp_v_w, tmp_o_w, W16,
      bias_in, ada_scale_b, pb_q_b, op_b, tr_out_b, tmp_q_b, tr_scale_b,
      BIASB, ZT,
      a_in, s_in, ada_snorm, tr_snorm, AN1, SN1, SN2, SBF);
  // 2: gates GEMM + AdaLN#1 dual fused (independent)
  gemm_pair<<<dim3(12, 64, 2), 256, 0, stream>>>(
      SBF, WGATES, BIASB + 4608, GATES, SN1, WADA1, BIASB + 0, AN1, SBF);
  // 3: qkvg
  gemm_bt<0><<<dim3(24, 64), 256, 0, stream>>>(SBF, WQKVG, BIASB + 1536, QKVG,
                                               nullptr, nullptr, 768, 768, 3072, 0);
  // 4: spatial attention (writes sigmoid(g)*o)
  attn_spatial<<<dim3(4, 12, 32), 256, 0, stream>>>(QKVG, ZT, OGO);
  // 5: a1 = a + gate_op * (go @ o_w)
  gemm_bt<3><<<dim3(6, 64), 256, 0, stream>>>(OGO, WO, nullptr, A1F, a_in, GATES,
                                              768, 768, 768, 1536);
  // 6: h = LN(a1)*w+b
  ln_affine<<<2048, 256, 0, stream>>>(A1F, tmp_ln_w, tmp_ln_b, AN1);
  // 7: temporal qkv
  gemm_bt<0><<<dim3(18, 64), 256, 0, stream>>>(AN1, WTMPQKV, BIASB + 6144, QKVG,
                                               nullptr, nullptr, 768, 768, 2304, 0);
  // 8: temporal attention
  attn_temporal<<<512, 256, 0, stream>>>(QKVG, ts, tmp_decay, OGO);
  // 9: a2 = a1 + tattn @ tmp_o_w   (in place)
  gemm_bt<2><<<dim3(6, 64), 256, 0, stream>>>(OGO, WTMPO, nullptr, A1F, A1F, nullptr,
                                              768, 768, 768, 0);
  // 10: an2 = LN(a2)
  ln_affine<<<2048, 256, 0, stream>>>(A1F, nullptr, nullptr, SN1);
  // 11: AdaLN #2 fused -> b2 in SBF
  gemm_dual<0><<<dim3(12, 64), 256, 0, stream>>>(SN2, WADA2, 768, BIASB + 8448, SN1,
                                                 SBF, 768);
  // 12: transition fused SwiGLU: hid = silu(b2@gate)*(b2@ab) -> CADA
  gemm_dual<1><<<dim3(24, 64), 256, 0, stream>>>(SBF, WTRANS, 1536, nullptr, nullptr,
                                                 CADA, 1536);
  // 13: out = a2 + gate_tr * (hid @ ba_w)
  gemm_bt<3><<<dim3(6, 64), 256, 0, stream>>>(CADA, WBA, nullptr, OUTF, A1F,
                                              GATES + 768, 1536, 1536, 768, 1536);
}

// Round 5
// 662.681 us; speedup vs baseline: 1.0549x; 1.0265x over previous
//
#include <hip/hip_runtime.h>

// ---------------------------------------------------------------------------
// Types / helpers
// ---------------------------------------------------------------------------
typedef short s16x8 __attribute__((ext_vector_type(8)));
typedef short s16x4 __attribute__((ext_vector_type(4)));
typedef float f32x4 __attribute__((ext_vector_type(4)));
typedef __bf16 bf16x8 __attribute__((ext_vector_type(8)));

__device__ __forceinline__ float bf2f(short u) {
  union { unsigned int i; float f; } c;
  c.i = ((unsigned int)(unsigned short)u) << 16;
  return c.f;
}
__device__ __forceinline__ short f2bf(float f) {
  union { float f; unsigned int i; } c; c.f = f;
  unsigned int r = c.i + 0x7FFFu + ((c.i >> 16) & 1u);  // RNE
  return (short)(r >> 16);
}
__device__ __forceinline__ float sigmoidf_(float x) { return 1.f / (1.f + __expf(-x)); }

template <typename T>
__device__ __forceinline__ auto mfma_sel(T a, T b, f32x4 c, int)
    -> decltype(__builtin_amdgcn_mfma_f32_16x16x32_bf16(a, b, c, 0, 0, 0)) {
  return __builtin_amdgcn_mfma_f32_16x16x32_bf16(a, b, c, 0, 0, 0);
}
template <typename T>
__device__ __forceinline__ f32x4 mfma_sel(T a, T b, f32x4 c, long) {
  return __builtin_amdgcn_mfma_f32_16x16x32_bf16(
      __builtin_bit_cast(bf16x8, a), __builtin_bit_cast(bf16x8, b), c, 0, 0, 0);
}
__device__ __forceinline__ f32x4 MFMA16(s16x8 a, s16x8 b, f32x4 c) {
  return mfma_sel(a, b, c, 0);
}

__device__ __forceinline__ void gl2lds16(const void* g, void* l) {
  __builtin_amdgcn_global_load_lds(
      (const __attribute__((address_space(1))) unsigned int*)g,
      (__attribute__((address_space(3))) unsigned int*)l, 16, 0, 0);
}

// ---------------------------------------------------------------------------
// Workspace layout (byte offsets)
// ---------------------------------------------------------------------------
#define OFF_WADA1    0u             // [1536][768] bf16 (scale^T | shift^T)
#define OFF_WQKVG    2359296u       // [3072][768] bf16 (q|k|v|g ^T)
#define OFF_WO       7077888u       // [768][768]
#define OFF_WGATES   8257536u       // [1536][768] (op^T | tr_out^T)
#define OFF_WTMPQKV  10616832u      // [2304][768]
#define OFF_WTMPO    14155776u      // [768][768]
#define OFF_WADA2    15335424u      // [1536][768]
#define OFF_WTRANS   17694720u      // [3072][768] (gate^T | ab^T)
#define OFF_WBA      22413312u      // [768][1536]
#define OFF_BIAS     24772608u      // 9984 floats
#define OFF_ZT       24812544u      // [2][12][256][256] bf16 (3 MB)
#define OFF_AN1      31104000u      // bf16 [8192][768]  (an1 / h)
#define OFF_SN1      43686912u      // bf16 [8192][768]  (sn1 / an2)
#define OFF_SN2      56269824u      // bf16 [8192][768]
#define OFF_SBF      68852736u      // bf16 [8192][768]  (s_bf / b_act / b2)
#define OFF_CADA     81435648u      // bf16 [8192][1536] (hid)
#define OFF_QKVG     106601472u     // bf16 [8192][3072] (qkvg / qkvt)
#define OFF_GATES    156933120u     // bf16 [8192][1536] (sigmoid gates: op | tr)
#define OFF_OGO      182098944u     // bf16 [8192][768]  (gated attn out / tattn)
#define OFF_A1       194681856u     // f32  [8192][768]  (a1, then a2 in-place)

// ---------------------------------------------------------------------------
// Mega prep kernel: z<18 weight transpose; z=18 zt transpose (coalesced) +
// bias assembly; z=19 ln_quad. Block dims (32,8).
// ---------------------------------------------------------------------------
__global__ __launch_bounds__(256) void prep_all(
    const float* p0, const float* p1, const float* p2, const float* p3,
    const float* p4, const float* p5, const float* p6, const float* p7,
    const float* p8, const float* p9, const float* p10, const float* p11,
    const float* p12, const float* p13, const float* p14, const float* p15,
    const float* p16, const float* p17, short* wsb,
    const float* __restrict__ zsrc, const float* __restrict__ ada_scale_b,
    const float* __restrict__ pb_q_b, const float* __restrict__ op_b,
    const float* __restrict__ tr_out_b, const float* __restrict__ tmp_q_b,
    const float* __restrict__ tr_scale_b,
    float* __restrict__ biasbuf, short* __restrict__ zt,
    const float* __restrict__ a_in, const float* __restrict__ s_in,
    const float* __restrict__ lnw1, const float* __restrict__ lnw2,
    short* __restrict__ an1, short* __restrict__ sn1, short* __restrict__ sn2,
    short* __restrict__ sbf) {
  const int z = blockIdx.z;
  const int tid = threadIdx.y * 32 + threadIdx.x;
  if (z < 18) {
    struct E { int K, N, dst; };
    const E tab[18] = {
        {768, 768, 0},        {768, 768, 589824},
        {768, 768, 1179648},  {768, 768, 1769472},
        {768, 768, 2359296},  {768, 768, 2949120},
        {768, 768, 3538944},
        {768, 768, 4128768},  {768, 768, 4718592},
        {768, 768, 7667712},  {768, 768, 8257536},
        {768, 1536, 8847360}, {768, 1536, 10027008},
        {1536, 768, 11206656},
        {768, 768, 5308416},  {768, 768, 5898240}, {768, 768, 6488064},
        {768, 768, 7077888}};
    int K = tab[z].K, N = tab[z].N;
    int n0 = blockIdx.x << 5, k0 = blockIdx.y << 5;
    if (n0 >= N || k0 >= K) return;
    const float* src;
    switch (z) {
      case 0: src = p0; break;  case 1: src = p1; break;
      case 2: src = p2; break;  case 3: src = p3; break;
      case 4: src = p4; break;  case 5: src = p5; break;
      case 6: src = p6; break;  case 7: src = p7; break;
      case 8: src = p8; break;  case 9: src = p9; break;
      case 10: src = p10; break; case 11: src = p11; break;
      case 12: src = p12; break; case 13: src = p13; break;
      case 14: src = p14; break; case 15: src = p15; break;
      case 16: src = p16; break; default: src = p17; break;
    }
    short* dst = wsb + tab[z].dst;
    __shared__ float tile[32][33];
    int tx = threadIdx.x, ty = threadIdx.y;
#pragma unroll
    for (int j = 0; j < 4; j++)
      tile[ty + j * 8][tx] = src[(long)(k0 + ty + j * 8) * N + n0 + tx];
    __syncthreads();
#pragma unroll
    for (int j = 0; j < 4; j++)
      dst[(long)(n0 + ty + j * 8) * K + k0 + tx] = f2bf(tile[tx][ty + j * 8]);
  } else if (z == 18) {
    const int bid = blockIdx.y * 48 + blockIdx.x;
    if (bid < 512) {
      const int b = bid >> 8, qq = bid & 255;
      const float* src = zsrc + (long)bid * 3072 + tid * 12;
      f32x4 v0 = *(const f32x4*)(src);
      f32x4 v1 = *(const f32x4*)(src + 4);
      f32x4 v2 = *(const f32x4*)(src + 8);
      float vals[12] = {v0[0], v0[1], v0[2], v0[3], v1[0], v1[1],
                        v1[2], v1[3], v2[0], v2[1], v2[2], v2[3]};
#pragma unroll
      for (int h = 0; h < 12; h++)
        zt[(((long)(b * 12 + h) * 256 + qq) << 8) + tid] = f2bf(vals[h]);
    } else if (bid < 551) {
      int j = (bid - 512) * 256 + tid;
      if (j < 9984) {
        float v;
        if (j < 1536) v = (j < 768) ? ada_scale_b[j] : 0.f;
        else if (j < 4608) { int jj = j - 1536; v = (jj < 768) ? pb_q_b[jj] : 0.f; }
        else if (j < 6144) { int jj = j - 4608; v = (jj < 768) ? op_b[jj] : tr_out_b[jj - 768]; }
        else if (j < 8448) { int jj = j - 6144; v = (jj < 768) ? tmp_q_b[jj] : 0.f; }
        else { int jj = j - 8448; v = (jj < 768) ? tr_scale_b[jj] : 0.f; }
        biasbuf[j] = v;
      }
    }
  } else {
    const int bid = blockIdx.y * 48 + blockIdx.x;
    if (bid >= 2048) return;
    const int wave = tid >> 6, lane = tid & 63;
    const int row = (bid << 2) + wave;
    const float* ar = a_in + (long)row * 768;
    const float* sr = s_in + (long)row * 768;
    f32x4 av[3], sv[3];
    float s0 = 0, s1 = 0, s2 = 0, s3 = 0;
#pragma unroll
    for (int k = 0; k < 3; k++) {
      int col = (lane << 2) + (k << 8);
      av[k] = *(const f32x4*)(ar + col);
      sv[k] = *(const f32x4*)(sr + col);
#pragma unroll
      for (int e = 0; e < 4; e++) {
        s0 += av[k][e]; s1 += av[k][e] * av[k][e];
        s2 += sv[k][e]; s3 += sv[k][e] * sv[k][e];
      }
    }
#pragma unroll
    for (int o = 32; o; o >>= 1) {
      s0 += __shfl_xor(s0, o, 64); s1 += __shfl_xor(s1, o, 64);
      s2 += __shfl_xor(s2, o, 64); s3 += __shfl_xor(s3, o, 64);
    }
    const float inv768 = 1.f / 768.f;
    float ma = s0 * inv768, va = s1 * inv768 - ma * ma;
    float ia = rsqrtf(va + 1e-5f);
    float ms = s2 * inv768, vs = s3 * inv768 - ms * ms;
    float is_ = rsqrtf(vs + 1e-5f);
#pragma unroll
    for (int k = 0; k < 3; k++) {
      int col = (lane << 2) + (k << 8);
      long o = (long)row * 768 + col;
      s16x4 o1, o2, o3, o4;
#pragma unroll
      for (int e = 0; e < 4; e++) {
        o1[e] = f2bf((av[k][e] - ma) * ia);
        float sn = (sv[k][e] - ms) * is_;
        o2[e] = f2bf(sn * lnw1[col + e]);
        o3[e] = f2bf(sn * lnw2[col + e]);
        o4[e] = f2bf(sv[k][e]);
      }
      *(s16x4*)(an1 + o) = o1;
      *(s16x4*)(sn1 + o) = o2;
      *(s16x4*)(sn2 + o) = o3;
      *(s16x4*)(sbf + o) = o4;
    }
  }
}

// ---------------------------------------------------------------------------
// ln_affine: wave-per-row, 4 rows/block
// ---------------------------------------------------------------------------
__global__ __launch_bounds__(256) void ln_affine(
    const float* __restrict__ in, const float* __restrict__ w,
    const float* __restrict__ b, short* __restrict__ out) {
  const int wave = threadIdx.x >> 6, lane = threadIdx.x & 63;
  const int row = (blockIdx.x << 2) + wave;
  const float* xr = in + (long)row * 768;
  f32x4 xv[3];
  float s0 = 0, s1 = 0;
#pragma unroll
  for (int k = 0; k < 3; k++) {
    int col = (lane << 2) + (k << 8);
    xv[k] = *(const f32x4*)(xr + col);
#pragma unroll
    for (int e = 0; e < 4; e++) { s0 += xv[k][e]; s1 += xv[k][e] * xv[k][e]; }
  }
#pragma unroll
  for (int o = 32; o; o >>= 1) { s0 += __shfl_xor(s0, o, 64); s1 += __shfl_xor(s1, o, 64); }
  const float inv768 = 1.f / 768.f;
  float m = s0 * inv768, v = s1 * inv768 - m * m;
  float inv = rsqrtf(v + 1e-5f);
#pragma unroll
  for (int k = 0; k < 3; k++) {
    int col = (lane << 2) + (k << 8);
    s16x4 p;
#pragma unroll
    for (int e = 0; e < 4; e++) {
      float y = (xv[k][e] - m) * inv;
      if (w) y = y * w[col + e] + b[col + e];
      p[e] = f2bf(y);
    }
    *(s16x4*)(out + (long)row * 768 + col) = p;
  }
}

// ---------------------------------------------------------------------------
// GEMM engine — 64(m)x128(n) tiles for residency (24 KB LDS, 32 AGPR acc).
// C[M][N] = A[M][K] @ W[N][K]^T; operand-swapped MFMA -> vectorized epilogue.
// Wave layout: wm = (wave&1)*32 (2 m-strips), wn = (wave>>1)*64 (2 n-strips).
// EP: 0 bf16(+bias), 1 bf16 sigmoid(+bias), 2 f32 res+acc, 3 f32 res+gate*acc
// ---------------------------------------------------------------------------
template <int EP>
__device__ __forceinline__ void dev_gemm_bt(
    short* lds,
    const short* __restrict__ A, const short* __restrict__ W,
    const float* __restrict__ bias, void* __restrict__ Cout,
    const float* __restrict__ res, const short* __restrict__ gate,
    int K, int ldA, int ldC, int gld) {
  short* sA = lds;          // 64x64  = 4096 shorts (8 KB)
  short* sB = lds + 4096;   // 128x64 = 8192 shorts (16 KB)
  const int tid = threadIdx.x;
  const int wave = tid >> 6, lane = tid & 63;
  const int m0 = blockIdx.y << 6;
  const int n0 = blockIdx.x << 7;
  const int wm = (wave & 1) << 5, wn = (wave >> 1) << 6;
  const int q = lane >> 4, r = lane & 15;
  f32x4 acc[2][4];
#pragma unroll
  for (int i = 0; i < 2; i++)
#pragma unroll
    for (int j = 0; j < 4; j++) acc[i][j] = (f32x4){0.f, 0.f, 0.f, 0.f};

  for (int kt = 0; kt < K; kt += 64) {
    __syncthreads();
#pragma unroll
    for (int t = 0; t < 2; t++) {  // A: 64 rows
      int c = (t << 8) + tid;
      int m = c >> 3, kc = (c & 7) ^ (m & 7);
      gl2lds16(A + (long)(m0 + m) * ldA + kt + (kc << 3),
               sA + (((t << 8) + (wave << 6)) << 3));
    }
#pragma unroll
    for (int t = 0; t < 4; t++) {  // B: 128 rows
      int c = (t << 8) + tid;
      int m = c >> 3, kc = (c & 7) ^ (m & 7);
      gl2lds16(W + (long)(n0 + m) * K + kt + (kc << 3),
               sB + (((t << 8) + (wave << 6)) << 3));
    }
    __syncthreads();
#pragma unroll
    for (int ks = 0; ks < 2; ks++) {
      s16x8 av[2], bv[4];
#pragma unroll
      for (int mt = 0; mt < 2; mt++) {
        int row = wm + (mt << 4) + r;
        int ch = ((ks << 2) + q) ^ (row & 7);
        av[mt] = *(const s16x8*)(sA + ((row << 3) + ch) * 8);
      }
#pragma unroll
      for (int nt = 0; nt < 4; nt++) {
        int row = wn + (nt << 4) + r;
        int ch = ((ks << 2) + q) ^ (row & 7);
        bv[nt] = *(const s16x8*)(sB + ((row << 3) + ch) * 8);
      }
#pragma unroll
      for (int mt = 0; mt < 2; mt++)
#pragma unroll
        for (int nt = 0; nt < 4; nt++)
          acc[mt][nt] = MFMA16(bv[nt], av[mt], acc[mt][nt]);  // swapped
    }
  }
#pragma unroll
  for (int mt = 0; mt < 2; mt++) {
    const int gm = m0 + wm + (mt << 4) + r;
#pragma unroll
    for (int nt = 0; nt < 4; nt++) {
      const int gnb = n0 + wn + (nt << 4) + (q << 2);
      f32x4 v = acc[mt][nt];
      if (bias) {
        f32x4 b4 = *(const f32x4*)(bias + gnb);
        v += b4;
      }
      long o = (long)gm * ldC + gnb;
      if (EP == 0) {
        s16x4 p;
#pragma unroll
        for (int e = 0; e < 4; e++) p[e] = f2bf(v[e]);
        *(s16x4*)((short*)Cout + o) = p;
      } else if (EP == 1) {
        s16x4 p;
#pragma unroll
        for (int e = 0; e < 4; e++) p[e] = f2bf(sigmoidf_(v[e]));
        *(s16x4*)((short*)Cout + o) = p;
      } else if (EP == 2) {
        f32x4 r4 = *(const f32x4*)(res + o);
        *(f32x4*)((float*)Cout + o) = r4 + v;
      } else {
        f32x4 r4 = *(const f32x4*)(res + o);
        s16x4 g4 = *(const s16x4*)(gate + (long)gm * gld + gnb);
        f32x4 out;
#pragma unroll
        for (int e = 0; e < 4; e++) out[e] = r4[e] + bf2f(g4[e]) * v[e];
        *(f32x4*)((float*)Cout + o) = out;
      }
    }
  }
}

// Dual GEMM + fused combine — 64(m)x64(n) tile of both W halves (24 KB LDS).
// MODE 0 (adaln): out = bf16( sigmoid(c1+bias)*an + c2 ); MODE 1: silu(c1)*c2
template <int MODE>
__device__ __forceinline__ void dev_gemm_dual(
    short* lds,
    const short* __restrict__ A, const short* __restrict__ W, int woff2,
    const float* __restrict__ bias, const short* __restrict__ an,
    short* __restrict__ out, int ldO) {
  short* sA = lds;            // 64x64 = 4096 shorts
  short* sB1 = lds + 4096;    // 64x64
  short* sB2 = lds + 8192;    // 64x64
  const int tid = threadIdx.x;
  const int wave = tid >> 6, lane = tid & 63;
  const int m0 = blockIdx.y << 6;
  const int n0 = blockIdx.x << 6;
  const int wm = (wave & 1) << 5, wn = (wave >> 1) << 5;
  const int q = lane >> 4, r = lane & 15;
  f32x4 acc1[2][2], acc2[2][2];
#pragma unroll
  for (int i = 0; i < 2; i++)
#pragma unroll
    for (int j = 0; j < 2; j++) {
      acc1[i][j] = (f32x4){0.f, 0.f, 0.f, 0.f};
      acc2[i][j] = (f32x4){0.f, 0.f, 0.f, 0.f};
    }

  for (int kt = 0; kt < 768; kt += 64) {
    __syncthreads();
#pragma unroll
    for (int t = 0; t < 2; t++) {
      int c = (t << 8) + tid;
      int m = c >> 3, kc = (c & 7) ^ (m & 7);
      gl2lds16(A + (long)(m0 + m) * 768 + kt + (kc << 3),
               sA + (((t << 8) + (wave << 6)) << 3));
      gl2lds16(W + (long)(n0 + m) * 768 + kt + (kc << 3),
               sB1 + (((t << 8) + (wave << 6)) << 3));
      gl2lds16(W + (long)(woff2 + n0 + m) * 768 + kt + (kc << 3),
               sB2 + (((t << 8) + (wave << 6)) << 3));
    }
    __syncthreads();
#pragma unroll
    for (int ks = 0; ks < 2; ks++) {
      s16x8 av[2], b1[2], b2[2];
#pragma unroll
      for (int mt = 0; mt < 2; mt++) {
        int row = wm + (mt << 4) + r;
        int ch = ((ks << 2) + q) ^ (row & 7);
        av[mt] = *(const s16x8*)(sA + ((row << 3) + ch) * 8);
      }
#pragma unroll
      for (int nt = 0; nt < 2; nt++) {
        int row = wn + (nt << 4) + r;
        int ch = ((ks << 2) + q) ^ (row & 7);
        b1[nt] = *(const s16x8*)(sB1 + ((row << 3) + ch) * 8);
        b2[nt] = *(const s16x8*)(sB2 + ((row << 3) + ch) * 8);
      }
#pragma unroll
      for (int mt = 0; mt < 2; mt++)
#pragma unroll
        for (int nt = 0; nt < 2; nt++) {
          acc1[mt][nt] = MFMA16(b1[nt], av[mt], acc1[mt][nt]);
          acc2[mt][nt] = MFMA16(b2[nt], av[mt], acc2[mt][nt]);
        }
    }
  }
#pragma unroll
  for (int mt = 0; mt < 2; mt++) {
    const int gm = m0 + wm + (mt << 4) + r;
#pragma unroll
    for (int nt = 0; nt < 2; nt++) {
      const int gnb = n0 + wn + (nt << 4) + (q << 2);
      s16x4 p;
      if (MODE == 0) {
        f32x4 b4 = *(const f32x4*)(bias + gnb);
        s16x4 an4 = *(const s16x4*)(an + (long)gm * 768 + gnb);
#pragma unroll
        for (int e = 0; e < 4; e++)
          p[e] = f2bf(sigmoidf_(acc1[mt][nt][e] + b4[e]) * bf2f(an4[e]) +
                      acc2[mt][nt][e]);
      } else {
#pragma unroll
        for (int e = 0; e < 4; e++) {
          float x = acc1[mt][nt][e];
          p[e] = f2bf(x * sigmoidf_(x) * acc2[mt][nt][e]);
        }
      }
      *(s16x4*)(out + (long)gm * ldO + gnb) = p;
    }
  }
}

template <int EP>
__global__ __launch_bounds__(256) void gemm_bt(
    const short* __restrict__ A, const short* __restrict__ W,
    const float* __restrict__ bias, void* __restrict__ Cout,
    const float* __restrict__ res, const short* __restrict__ gate,
    int K, int ldA, int ldC, int gld) {
  __shared__ short lds[12288];
  dev_gemm_bt<EP>(lds, A, W, bias, Cout, res, gate, K, ldA, ldC, gld);
}

template <int MODE>
__global__ __launch_bounds__(256) void gemm_dual(
    const short* __restrict__ A, const short* __restrict__ W, int woff2,
    const float* __restrict__ bias, const short* __restrict__ an,
    short* __restrict__ out, int ldO) {
  __shared__ short lds[12288];
  dev_gemm_dual<MODE>(lds, A, W, woff2, bias, an, out, ldO);
}

// Fused independent pair: z=0 gates GEMM (sigmoid), z=1 AdaLN#1 dual.
__global__ __launch_bounds__(256) void gemm_pair(
    const short* __restrict__ sbf, const short* __restrict__ wgates,
    const float* __restrict__ bias_g, short* __restrict__ gates,
    const short* __restrict__ sn1, const short* __restrict__ wada1,
    const float* __restrict__ bias_a, const short* __restrict__ an1,
    short* __restrict__ outb) {
  __shared__ short lds[12288];
  if (blockIdx.z == 0)
    dev_gemm_bt<1>(lds, sbf, wgates, bias_g, (void*)gates, nullptr, nullptr,
                   768, 768, 1536, 0);
  else
    dev_gemm_dual<0>(lds, sn1, wada1, 768, bias_a, an1, outb, 768);
}

// ---------------------------------------------------------------------------
// Spatial attention: block per (qtile64, h, bt). MFMA QK^T + softmax + MFMA PV.
// ---------------------------------------------------------------------------
__global__ __launch_bounds__(256) void attn_spatial(
    const short* __restrict__ qkvg, const short* __restrict__ zt, short* __restrict__ ogo) {
  __shared__ short sKP[256 * 64];  // K tile, later P
  __shared__ short sVt[64 * 256];  // V^T [d][tok]
  const int tid = threadIdx.x;
  const int wave = tid >> 6, lane = tid & 63;
  const int qt = blockIdx.x, h = blockIdx.y, bt = blockIdx.z;
  const int b = bt >> 4;
  const int q0 = qt << 6;
  const long rowbase = (long)bt << 8;
  const int hoff = h << 6;

#pragma unroll
  for (int t = 0; t < 8; t++) {  // K stage (swizzled)
    int c = (t << 8) + tid;
    int tok = c >> 3, kc = (c & 7) ^ (tok & 7);
    *(s16x8*)(sKP + (c << 3)) =
        *(const s16x8*)(qkvg + (rowbase + tok) * 3072 + 768 + hoff + (kc << 3));
  }
#pragma unroll
  for (int t = 0; t < 8; t++) {  // V^T stage
    int u = (t << 8) + tid;
    int tok = u >> 3, dc = u & 7;
    s16x8 v8 = *(const s16x8*)(qkvg + (rowbase + tok) * 3072 + 1536 + hoff + (dc << 3));
#pragma unroll
    for (int e = 0; e < 8; e++) {
      int d = (dc << 3) + e;
      int ch = (tok >> 3) ^ (d & 7);
      sVt[((d << 5) + ch) * 8 + (tok & 7)] = v8[e];
    }
  }
  __syncthreads();

  const int q = lane >> 4, cc = lane & 15;
  f32x4 acc[16];
#pragma unroll
  for (int i = 0; i < 16; i++) acc[i] = (f32x4){0.f, 0.f, 0.f, 0.f};
  {
    const int arow = (wave << 4) + cc;
    const short* qrow = qkvg + (rowbase + q0 + arow) * 3072 + hoff;
#pragma unroll
    for (int ks = 0; ks < 2; ks++) {
      s16x8 av = *(const s16x8*)(qrow + (ks << 5) + (q << 3));
#pragma unroll
      for (int nt = 0; nt < 16; nt++) {
        int tok = (nt << 4) + cc;
        int chb = ((ks << 2) + q) ^ (tok & 7);
        s16x8 bv = *(const s16x8*)(sKP + ((tok << 3) + chb) * 8);
        acc[nt] = MFMA16(av, bv, acc[nt]);
      }
    }
  }
  const short* ztb = zt + (((long)(b * 12 + h) * 256 + q0 + (wave << 4)) << 8);
#pragma unroll
  for (int reg = 0; reg < 4; reg++) {
    int lr = (q << 2) + reg;
    float mx = -3.0e38f;
#pragma unroll
    for (int nt = 0; nt < 16; nt++) {
      float v = acc[nt][reg] * 0.125f + bf2f(ztb[lr * 256 + (nt << 4) + cc]);
      acc[nt][reg] = v;
      mx = fmaxf(mx, v);
    }
    mx = fmaxf(mx, __shfl_xor(mx, 1, 16));
    mx = fmaxf(mx, __shfl_xor(mx, 2, 16));
    mx = fmaxf(mx, __shfl_xor(mx, 4, 16));
    mx = fmaxf(mx, __shfl_xor(mx, 8, 16));
    float sum = 0.f;
#pragma unroll
    for (int nt = 0; nt < 16; nt++) {
      float e = __expf(acc[nt][reg] - mx);
      acc[nt][reg] = e; sum += e;
    }
    sum += __shfl_xor(sum, 1, 16);
    sum += __shfl_xor(sum, 2, 16);
    sum += __shfl_xor(sum, 4, 16);
    sum += __shfl_xor(sum, 8, 16);
    float inv = 1.f / sum;
#pragma unroll
    for (int nt = 0; nt < 16; nt++) acc[nt][reg] *= inv;
  }
  __syncthreads();
#pragma unroll
  for (int nt = 0; nt < 16; nt++) {
#pragma unroll
    for (int reg = 0; reg < 4; reg++) {
      int rP = (wave << 4) + (q << 2) + reg;
      int col = (nt << 4) + cc;
      int ch = (col >> 3) ^ (rP & 7);
      sKP[((rP << 5) + ch) * 8 + (col & 7)] = f2bf(acc[nt][reg]);
    }
  }
  __syncthreads();
  f32x4 oacc[4];
#pragma unroll
  for (int i = 0; i < 4; i++) oacc[i] = (f32x4){0.f, 0.f, 0.f, 0.f};
  const int prow = (wave << 4) + cc;
#pragma unroll
  for (int ksi = 0; ksi < 8; ksi++) {
    int cha = ((ksi << 2) + q) ^ (prow & 7);
    s16x8 pa = *(const s16x8*)(sKP + ((prow << 5) + cha) * 8);
#pragma unroll
    for (int dt = 0; dt < 4; dt++) {
      int d = (dt << 4) + cc;
      int chv = ((ksi << 2) + q) ^ (d & 7);
      s16x8 bv = *(const s16x8*)(sVt + ((d << 5) + chv) * 8);
      oacc[dt] = MFMA16(pa, bv, oacc[dt]);
    }
  }
#pragma unroll
  for (int dt = 0; dt < 4; dt++) {
#pragma unroll
    for (int reg = 0; reg < 4; reg++) {
      int rowt = q0 + (wave << 4) + (q << 2) + reg;
      int dcol = (dt << 4) + cc;
      long grow = rowbase + rowt;
      float gl = bf2f(qkvg[grow * 3072 + 2304 + hoff + dcol]);
      ogo[grow * 768 + hoff + dcol] = f2bf(oacc[dt][reg] * sigmoidf_(gl));
    }
  }
}

// ---------------------------------------------------------------------------
// Temporal attention: block per (b,n).
// ---------------------------------------------------------------------------
__global__ __launch_bounds__(256) void attn_temporal(
    const short* __restrict__ qkvt, const float* __restrict__ ts,
    const float* __restrict__ decay_raw, short* __restrict__ out) {
  __shared__ short sKV[16 * 1544];
  const int bn = blockIdx.x;
  const int b = bn >> 8, n = bn & 255;
  const int tid = threadIdx.x;
#pragma unroll
  for (int t = 0; t < 12; t++) {
    int u = t * 256 + tid;
    int row = u / 192, cc = u % 192;
    *(s16x8*)(sKV + row * 1544 + cc * 8) =
        *(const s16x8*)(qkvt + ((long)(b * 16 + row) * 256 + n) * 2304 + 768 + cc * 8);
  }
  __syncthreads();
  const int h = tid >> 4, tq = tid & 15;
  if (h < 12) {
    const int hoff = h << 6;
    float dec = log1pf(__expf(decay_raw[h]));
    float tsq = ts[b * 16 + tq];
    s16x8 qv[8];
    const short* qrow = qkvt + ((long)(b * 16 + tq) * 256 + n) * 2304 + hoff;
#pragma unroll
    for (int dc = 0; dc < 8; dc++) qv[dc] = *(const s16x8*)(qrow + dc * 8);
    float sc[16];
#pragma unroll
    for (int tk = 0; tk < 16; tk++) {
      float dot = 0.f;
#pragma unroll
      for (int dc = 0; dc < 8; dc++) {
        s16x8 kv = *(const s16x8*)(sKV + tk * 1544 + hoff + dc * 8);
#pragma unroll
        for (int e = 0; e < 8; e++) dot += bf2f(qv[dc][e]) * bf2f(kv[e]);
      }
      sc[tk] = dot * 0.125f - dec * fabsf(tsq - ts[b * 16 + tk]);
    }
    float mx = sc[0];
#pragma unroll
    for (int tk = 1; tk < 16; tk++) mx = fmaxf(mx, sc[tk]);
    float sum = 0.f;
#pragma unroll
    for (int tk = 0; tk < 16; tk++) { sc[tk] = __expf(sc[tk] - mx); sum += sc[tk]; }
    float inv = 1.f / sum;
    float oa[64];
#pragma unroll
    for (int d = 0; d < 64; d++) oa[d] = 0.f;
#pragma unroll
    for (int tk = 0; tk < 16; tk++) {
      float wgt = sc[tk] * inv;
#pragma unroll
      for (int dc = 0; dc < 8; dc++) {
        s16x8 vv = *(const s16x8*)(sKV + tk * 1544 + 768 + hoff + dc * 8);
#pragma unroll
        for (int e = 0; e < 8; e++) oa[dc * 8 + e] += wgt * bf2f(vv[e]);
      }
    }
    long orow = (long)(b * 16 + tq) * 256 + n;
#pragma unroll
    for (int dc = 0; dc < 8; dc++) {
      s16x8 o8;
#pragma unroll
      for (int e = 0; e < 8; e++) o8[e] = f2bf(oa[dc * 8 + e]);
      *(s16x8*)(out + orow * 768 + hoff + dc * 8) = o8;
    }
  }
}

// ---------------------------------------------------------------------------
// Host launcher
// ---------------------------------------------------------------------------
extern "C" void kernel_launch(void* const* d_in, const int* in_sizes, int n_in,
                              void* d_out, int out_size, void* d_ws, size_t ws_size,
                              hipStream_t stream) {
  (void)in_sizes; (void)n_in; (void)out_size; (void)ws_size;
  const float* a_in      = (const float*)d_in[0];
  const float* s_in      = (const float*)d_in[1];
  const float* bias_in   = (const float*)d_in[2];
  const float* ts        = (const float*)d_in[4];
  const float* ada_snorm = (const float*)d_in[7];
  const float* ada_scale_w = (const float*)d_in[8];
  const float* ada_scale_b = (const float*)d_in[9];
  const float* ada_shift_w = (const float*)d_in[10];
  const float* pb_q_w = (const float*)d_in[11];
  const float* pb_q_b = (const float*)d_in[12];
  const float* pb_k_w = (const float*)d_in[13];
  const float* pb_v_w = (const float*)d_in[14];
  const float* pb_g_w = (const float*)d_in[15];
  const float* pb_o_w = (const float*)d_in[16];
  const float* op_w = (const float*)d_in[17];
  const float* op_b = (const float*)d_in[18];
  const float* tr_snorm = (const float*)d_in[19];
  const float* tr_scale_w = (const float*)d_in[20];
  const float* tr_scale_b = (const float*)d_in[21];
  const float* tr_shift_w = (const float*)d_in[22];
  const float* tr_gate_w = (const float*)d_in[23];
  const float* tr_ab_w = (const float*)d_in[24];
  const float* tr_ba_w = (const float*)d_in[25];
  const float* tr_out_w = (const float*)d_in[26];
  const float* tr_out_b = (const float*)d_in[27];
  const float* tmp_ln_w = (const float*)d_in[28];
  const float* tmp_ln_b = (const float*)d_in[29];
  const float* tmp_q_w = (const float*)d_in[30];
  const float* tmp_q_b = (const float*)d_in[31];
  const float* tmp_k_w = (const float*)d_in[32];
  const float* tmp_v_w = (const float*)d_in[33];
  const float* tmp_decay = (const float*)d_in[34];
  const float* tmp_o_w = (const float*)d_in[35];

  char* ws = (char*)d_ws;
  short* W16 = (short*)ws;
  short* WADA1 = (short*)(ws + OFF_WADA1);
  short* WQKVG = (short*)(ws + OFF_WQKVG);
  short* WO = (short*)(ws + OFF_WO);
  short* WGATES = (short*)(ws + OFF_WGATES);
  short* WTMPQKV = (short*)(ws + OFF_WTMPQKV);
  short* WTMPO = (short*)(ws + OFF_WTMPO);
  short* WADA2 = (short*)(ws + OFF_WADA2);
  short* WTRANS = (short*)(ws + OFF_WTRANS);
  short* WBA = (short*)(ws + OFF_WBA);
  float* BIASB = (float*)(ws + OFF_BIAS);
  short* ZT = (short*)(ws + OFF_ZT);
  short* AN1 = (short*)(ws + OFF_AN1);
  short* SN1 = (short*)(ws + OFF_SN1);
  short* SN2 = (short*)(ws + OFF_SN2);
  short* SBF = (short*)(ws + OFF_SBF);
  short* CADA = (short*)(ws + OFF_CADA);
  short* QKVG = (short*)(ws + OFF_QKVG);
  short* GATES = (short*)(ws + OFF_GATES);
  short* OGO = (short*)(ws + OFF_OGO);
  float* A1F = (float*)(ws + OFF_A1);
  float* OUTF = (float*)d_out;

  // 1: all prep + ln_quad in one dispatch
  prep_all<<<dim3(48, 48, 20), dim3(32, 8, 1), 0, stream>>>(
      ada_scale_w, ada_shift_w, pb_q_w, pb_k_w, pb_v_w, pb_g_w, pb_o_w,
      op_w, tr_out_w, tr_scale_w, tr_shift_w, tr_gate_w, tr_ab_w, tr_ba_w,
      tmp_q_w, tmp_k_w, tmp_v_w, tmp_o_w, W16,
      bias_in, ada_scale_b, pb_q_b, op_b, tr_out_b, tmp_q_b, tr_scale_b,
      BIASB, ZT,
      a_in, s_in, ada_snorm, tr_snorm, AN1, SN1, SN2, SBF);
  // 2: gates GEMM + AdaLN#1 dual fused (independent)
  gemm_pair<<<dim3(12, 128, 2), 256, 0, stream>>>(
      SBF, WGATES, BIASB + 4608, GATES, SN1, WADA1, BIASB + 0, AN1, SBF);
  // 3: qkvg
  gemm_bt<0><<<dim3(24, 128), 256, 0, stream>>>(SBF, WQKVG, BIASB + 1536, QKVG,
                                                nullptr, nullptr, 768, 768, 3072, 0);
  // 4: spatial attention (writes sigmoid(g)*o)
  attn_spatial<<<dim3(4, 12, 32), 256, 0, stream>>>(QKVG, ZT, OGO);
  // 5: a1 = a + gate_op * (go @ o_w)
  gemm_bt<3><<<dim3(6, 128), 256, 0, stream>>>(OGO, WO, nullptr, A1F, a_in, GATES,
                                               768, 768, 768, 1536);
  // 6: h = LN(a1)*w+b
  ln_affine<<<2048, 256, 0, stream>>>(A1F, tmp_ln_w, tmp_ln_b, AN1);
  // 7: temporal qkv
  gemm_bt<0><<<dim3(18, 128), 256, 0, stream>>>(AN1, WTMPQKV, BIASB + 6144, QKVG,
                                                nullptr, nullptr, 768, 768, 2304, 0);
  // 8: temporal attention
  attn_temporal<<<512, 256, 0, stream>>>(QKVG, ts, tmp_decay, OGO);
  // 9: a2 = a1 + tattn @ tmp_o_w   (in place)
  gemm_bt<2><<<dim3(6, 128), 256, 0, stream>>>(OGO, WTMPO, nullptr, A1F, A1F, nullptr,
                                               768, 768, 768, 0);
  // 10: an2 = LN(a2)
  ln_affine<<<2048, 256, 0, stream>>>(A1F, nullptr, nullptr, SN1);
  // 11: AdaLN #2 fused -> b2 in SBF
  gemm_dual<0><<<dim3(12, 128), 256, 0, stream>>>(SN2, WADA2, 768, BIASB + 8448, SN1,
                                                  SBF, 768);
  // 12: transition fused SwiGLU: hid = silu(b2@gate)*(b2@ab) -> CADA
  gemm_dual<1><<<dim3(24, 128), 256, 0, stream>>>(SBF, WTRANS, 1536, nullptr, nullptr,
                                                  CADA, 1536);
  // 13: out = a2 + gate_tr * (hid @ ba_w)
  gemm_bt<3><<<dim3(6, 128), 256, 0, stream>>>(CADA, WBA, nullptr, OUTF, A1F,
                                               GATES + 768, 1536, 1536, 768, 1536);
}